// Round 4
// baseline (3290.930 us; speedup 1.0000x reference)
//
#include <hip/hip_runtime.h>
#include <cmath>

// ---------------------------------------------------------------------------
// ACT classifier (B=65536, D=512, H=256, C=100, T=10).
// Round 4: identical math to round 3 (f16 2-split MFMA, 2^8 pre-scale,
// fp32-exact halt path). ONE change: removed __launch_bounds__(256,2) from
// k_xproj / k_gru — the 128-VGPR cap forced register spills (demand ~170
// VGPR: 96 acc + 32 frags + staging temps), and HBM-backed spill traffic
// dominated rounds 2-3. Occupancy is LDS-bound at 2 blocks/CU either way.
// ---------------------------------------------------------------------------

namespace {
constexpr int B = 65536, D = 512, H = 256, C = 100, T = 10;

// output layout (flat float elements, reference return order)
constexpr long OUT_LOGITS = 0;
constexpr long OUT_PONDER = (long)B * C;
constexpr long OUT_NUP    = OUT_PONDER + 1;
constexpr long OUT_HSEQ   = OUT_NUP + B;
constexpr long OUT_HALT   = OUT_HSEQ + (long)B * T * H;
constexpr long OUT_LSEQ   = OUT_HALT + (long)B * T;

// weight plane sizes (elements)
constexpr long NIH  = 768L * D;   // 393216
constexpr long NHH  = 768L * H;   // 196608
constexpr long NAUG = 112L * H;   // 28672

// workspace layout (float units)
constexpr long WS_XP   = 0;                          // x_proj [B][768] f32
constexpr long WS_W16  = WS_XP + (long)B * 768;      // f16 planes (2x each W)
constexpr long W_HALV  = 2 * (NIH + NHH + NAUG);
constexpr long WS_HL   = WS_W16 + (W_HALV + 1) / 2;  // step_w [B][T]
constexpr long WS_HP4  = WS_HL + (long)B * T;        // halt partials [4][B]
constexpr long WS_NUPB = WS_HP4 + 4L * B;
constexpr long WS_REMB = WS_NUPB + B;

constexpr float SC = 256.f;            // operand pre-scale 2^8
constexpr float SB = 1.f / 65536.f;    // product scale-back 2^-16 (exact)
} // namespace

typedef __attribute__((ext_vector_type(8))) _Float16 h8;
typedef __attribute__((ext_vector_type(4))) _Float16 h4;
typedef __attribute__((ext_vector_type(4))) float f4;

#define MFMA16(A, Bo, Cc) __builtin_amdgcn_mfma_f32_16x16x32_f16(A, Bo, Cc, 0, 0, 0)
// 3-product 2-split accumulate, smallest first
#define PROD3(a, Ah, Al, Bh, Bl)                                               \
  a = MFMA16(Al, Bh, a);                                                       \
  a = MFMA16(Ah, Bl, a);                                                       \
  a = MFMA16(Ah, Bh, a);

__device__ __forceinline__ float sigmoidf_(float x) {
  if (x >= 0.f) { return 1.f / (1.f + expf(-x)); }
  float e = expf(x);
  return e / (1.f + e);
}

// ---------------------------------------------------------------------------
// split weights (pre-scaled by 2^8) into f16 hi/lo planes
__global__ void k_prep(const float* __restrict__ wih_s, const float* __restrict__ whh_s,
                       const float* __restrict__ wro, const float* __restrict__ whalt,
                       _Float16* __restrict__ wr) {
  long idx = (long)blockIdx.x * 256 + threadIdx.x;
  if (idx < NIH) {
    float xs = wih_s[idx] * SC;
    _Float16 h = (_Float16)xs;
    _Float16 l = (_Float16)(xs - (float)h);
    wr[idx] = h; wr[NIH + idx] = l;
  }
  if (idx < NHH) {
    float xs = whh_s[idx] * SC;
    _Float16 h = (_Float16)xs;
    _Float16 l = (_Float16)(xs - (float)h);
    long b = 2 * NIH;
    wr[b + idx] = h; wr[b + NHH + idx] = l;
  }
  if (idx < NAUG) {
    int row = (int)(idx >> 8), k = (int)(idx & 255);
    float x = (row < C) ? wro[row * 256 + k] : ((row == C) ? whalt[k] : 0.f);
    float xs = x * SC;
    _Float16 h = (_Float16)xs;
    _Float16 l = (_Float16)(xs - (float)h);
    long b = 2 * (NIH + NHH);
    wr[b + idx] = h; wr[b + NAUG + idx] = l;
  }
}

// stage 16 fp32 elems (scaled) as f16 hi/lo into LDS at row*40+kk0
__device__ __forceinline__ void stageA16(const float* __restrict__ src,
                                         _Float16* As0, _Float16* As1,
                                         int o) {
#pragma unroll
  for (int i = 0; i < 4; ++i) {
    float4 v = ((const float4*)src)[i];
    float vv[4] = {v.x, v.y, v.z, v.w};
    h4 hh, ll;
#pragma unroll
    for (int c = 0; c < 4; ++c) {
      float sv = vv[c] * SC;
      _Float16 h = (_Float16)sv;
      hh[c] = h;
      ll[c] = (_Float16)(sv - (float)h);
    }
    *(h4*)&As0[o + i * 4] = hh;
    *(h4*)&As1[o + i * 4] = ll;
  }
}

// ---------------------------------------------------------------------------
// xp = x @ W_ih^T + b_ih.  Grid 2048 (XCD-swizzled: 512 row-tiles x 4 strips).
__global__ void k_xproj(
    const float* __restrict__ x, const _Float16* __restrict__ wih,
    const float* __restrict__ b_ih, float* __restrict__ xp) {
  __shared__ __align__(16) _Float16 As0[128 * 40], As1[128 * 40];
  __shared__ __align__(16) _Float16 Bs0[192 * 40], Bs1[192 * 40];
  const int tid = threadIdx.x;
  const int w = tid >> 6, l = tid & 63;
  const int lr = l & 15, lq = l >> 4;
  const int bid = blockIdx.x;
  const int gid = (bid & 7) * 256 + (bid >> 3);   // XCD-contiguous
  const int c0 = (gid & 3) * 64;
  const int rb = (gid >> 2) * 128;

  f4 acc[8][3];
#pragma unroll
  for (int i = 0; i < 8; ++i)
#pragma unroll
    for (int g = 0; g < 3; ++g) acc[i][g] = (f4)0.f;

  for (int kc = 0; kc < 16; ++kc) {
    const int k0 = kc * 32;
    __syncthreads();
    {  // stage A (x rows, scaled split)
      const int row = tid >> 1, kk0 = (tid & 1) * 16;
      stageA16(x + (long)(rb + row) * D + k0 + kk0, As0, As1, row * 40 + kk0);
    }
#pragma unroll
    for (int it = 0; it < 3; ++it) {  // stage B
      int idx = tid + it * 256;  // < 768
      int scol = idx >> 2, kg = idx & 3;
      int gcol = (scol >> 6) * 256 + c0 + (scol & 63);
      *(h8*)&Bs0[scol * 40 + kg * 8] = *(const h8*)(wih + (long)gcol * D + k0 + kg * 8);
      *(h8*)&Bs1[scol * 40 + kg * 8] = *(const h8*)(wih + NIH + (long)gcol * D + k0 + kg * 8);
    }
    __syncthreads();
    h8 Bh[3], Bl[3];
#pragma unroll
    for (int g = 0; g < 3; ++g) {
      Bh[g] = *(const h8*)&Bs0[(g * 64 + w * 16 + lr) * 40 + lq * 8];
      Bl[g] = *(const h8*)&Bs1[(g * 64 + w * 16 + lr) * 40 + lq * 8];
    }
#pragma unroll
    for (int i = 0; i < 8; ++i) {
      h8 Ah = *(const h8*)&As0[(i * 16 + lr) * 40 + lq * 8];
      h8 Al = *(const h8*)&As1[(i * 16 + lr) * 40 + lq * 8];
#pragma unroll
      for (int g = 0; g < 3; ++g) { PROD3(acc[i][g], Ah, Al, Bh[g], Bl[g]); }
    }
  }
  const int ch = c0 + w * 16 + lr;
  float bi[3] = {b_ih[ch], b_ih[256 + ch], b_ih[512 + ch]};
#pragma unroll
  for (int i = 0; i < 8; ++i)
#pragma unroll
    for (int g = 0; g < 3; ++g)
#pragma unroll
      for (int reg = 0; reg < 4; ++reg) {
        long row = rb + i * 16 + lq * 4 + reg;
        xp[row * 768 + g * 256 + ch] = fmaf(acc[i][g][reg], SB, bi[g]);
      }
}

// ---------------------------------------------------------------------------
// One GRU step + fp32-exact halt partial dot per 64-col strip.
__global__ void k_gru(
    const _Float16* __restrict__ whh, const float* __restrict__ xp,
    const float* __restrict__ b_hh, const float* __restrict__ w_halt,
    float* __restrict__ out, float* __restrict__ hp4, int t) {
  __shared__ __align__(16) _Float16 As0[128 * 40], As1[128 * 40];
  __shared__ __align__(16) _Float16 Bs0[192 * 40], Bs1[192 * 40];
  __shared__ float lds_hp[128][4];
  const int tid = threadIdx.x;
  const int w = tid >> 6, l = tid & 63;
  const int lr = l & 15, lq = l >> 4;
  const int bid = blockIdx.x;
  const int gid = (bid & 7) * 256 + (bid >> 3);
  const int strip = gid & 3;
  const int c0 = strip * 64;
  const int rb = (gid >> 2) * 128;

  f4 acc[8][3];
#pragma unroll
  for (int i = 0; i < 8; ++i)
#pragma unroll
    for (int g = 0; g < 3; ++g) acc[i][g] = (f4)0.f;

  if (t > 0) {
    for (int kc = 0; kc < 8; ++kc) {
      const int k0 = kc * 32;
      __syncthreads();
      {  // stage A = h_{t-1}
        const int row = tid >> 1, kk0 = (tid & 1) * 16;
        stageA16(out + OUT_HSEQ + (long)(rb + row) * (T * H) + (long)(t - 1) * H + k0 + kk0,
                 As0, As1, row * 40 + kk0);
      }
#pragma unroll
      for (int it = 0; it < 3; ++it) {  // stage B (W_hh planes)
        int idx = tid + it * 256;
        int scol = idx >> 2, kg = idx & 3;
        int gcol = (scol >> 6) * 256 + c0 + (scol & 63);
        *(h8*)&Bs0[scol * 40 + kg * 8] = *(const h8*)(whh + (long)gcol * H + k0 + kg * 8);
        *(h8*)&Bs1[scol * 40 + kg * 8] = *(const h8*)(whh + NHH + (long)gcol * H + k0 + kg * 8);
      }
      __syncthreads();
      h8 Bh[3], Bl[3];
#pragma unroll
      for (int g = 0; g < 3; ++g) {
        Bh[g] = *(const h8*)&Bs0[(g * 64 + w * 16 + lr) * 40 + lq * 8];
        Bl[g] = *(const h8*)&Bs1[(g * 64 + w * 16 + lr) * 40 + lq * 8];
      }
#pragma unroll
      for (int i = 0; i < 8; ++i) {
        h8 Ah = *(const h8*)&As0[(i * 16 + lr) * 40 + lq * 8];
        h8 Al = *(const h8*)&As1[(i * 16 + lr) * 40 + lq * 8];
#pragma unroll
        for (int g = 0; g < 3; ++g) { PROD3(acc[i][g], Ah, Al, Bh[g], Bl[g]); }
      }
    }
  }

  // epilogue: gates + h_new + halt partial
  const int ch = c0 + w * 16 + lr;
  const float bhr = b_hh[ch], bhz = b_hh[256 + ch], bhn = b_hh[512 + ch];
  const float whv = w_halt[ch];
#pragma unroll
  for (int i = 0; i < 8; ++i)
#pragma unroll
    for (int reg = 0; reg < 4; ++reg) {
      const int rloc = i * 16 + lq * 4 + reg;
      const long row = rb + rloc;
      float xr = xp[row * 768 + ch];
      float xz = xp[row * 768 + 256 + ch];
      float xn = xp[row * 768 + 512 + ch];
      float ho = (t > 0) ? out[OUT_HSEQ + row * (T * H) + (long)(t - 1) * H + ch] : 0.f;
      float rr = sigmoidf_(xr + fmaf(acc[i][0][reg], SB, bhr));
      float zz = sigmoidf_(xz + fmaf(acc[i][1][reg], SB, bhz));
      float nn = tanhf(xn + rr * fmaf(acc[i][2][reg], SB, bhn));
      float hv = (1.f - zz) * nn + zz * ho;
      out[OUT_HSEQ + row * (T * H) + (long)t * H + ch] = hv;
      // halt partial over this wave's 16 cols (fp32 shuffle tree)
      float p = hv * whv;
#pragma unroll
      for (int m = 1; m < 16; m <<= 1) p += __shfl_xor(p, m, 64);
      if (lr == 0) lds_hp[rloc][w] = p;
    }
  __syncthreads();
  if (tid < 128)
    hp4[(long)strip * B + rb + tid] =
        ((lds_hp[tid][0] + lds_hp[tid][1]) + (lds_hp[tid][2] + lds_hp[tid][3]));
}

// ---------------------------------------------------------------------------
// halt[b,t] = sigmoid(b_halt + sum of 4 strip partials), fixed order.
__global__ void k_sumhp(const float* __restrict__ hp4, const float* __restrict__ b_halt,
                        float* __restrict__ out, int t) {
  const long b = (long)blockIdx.x * 256 + threadIdx.x;
  float v = b_halt[0] + hp4[b] + hp4[B + b] + hp4[2L * B + b] + hp4[3L * B + b];
  out[OUT_HALT + b * T + t] = sigmoidf_(v);
}

// ---------------------------------------------------------------------------
// Readout: [B*T,256] x [256,112] single-product f16 (cols 0..99 kept).
__global__ __launch_bounds__(256, 4) void k_lseq(
    const float* __restrict__ hseq, const _Float16* __restrict__ waug,
    const float* __restrict__ b_ro, float* __restrict__ lseq) {
  __shared__ __align__(16) _Float16 As0[128 * 40];
  __shared__ __align__(16) _Float16 Bs0[112 * 40];
  const int tid = threadIdx.x;
  const int w = tid >> 6, l = tid & 63;
  const int lr = l & 15, lq = l >> 4;
  const long mb = (long)blockIdx.x * 128;

  f4 acc[2][7];
#pragma unroll
  for (int i = 0; i < 2; ++i)
#pragma unroll
    for (int j = 0; j < 7; ++j) acc[i][j] = (f4)0.f;

  for (int kc = 0; kc < 8; ++kc) {
    const int k0 = kc * 32;
    __syncthreads();
    {  // stage A hi-plane only
      const int row = tid >> 1, kk0 = (tid & 1) * 16;
      const float* src = hseq + (mb + row) * H + k0 + kk0;
      const int o = row * 40 + kk0;
#pragma unroll
      for (int i = 0; i < 4; ++i) {
        float4 v = ((const float4*)src)[i];
        h4 hh;
        hh[0] = (_Float16)(v.x * SC); hh[1] = (_Float16)(v.y * SC);
        hh[2] = (_Float16)(v.z * SC); hh[3] = (_Float16)(v.w * SC);
        *(h4*)&As0[o + i * 4] = hh;
      }
    }
#pragma unroll
    for (int it = 0; it < 2; ++it) {  // stage B hi-plane
      int idx = tid + it * 256;
      if (idx < 448) {
        int scol = idx >> 2, kg = idx & 3;
        *(h8*)&Bs0[scol * 40 + kg * 8] = *(const h8*)(waug + (long)scol * H + k0 + kg * 8);
      }
    }
    __syncthreads();
    h8 Af[2];
#pragma unroll
    for (int i = 0; i < 2; ++i)
      Af[i] = *(const h8*)&As0[(w * 32 + i * 16 + lr) * 40 + lq * 8];
#pragma unroll
    for (int j = 0; j < 7; ++j) {
      h8 Bf = *(const h8*)&Bs0[(j * 16 + lr) * 40 + lq * 8];
#pragma unroll
      for (int i = 0; i < 2; ++i) acc[i][j] = MFMA16(Af[i], Bf, acc[i][j]);
    }
  }
#pragma unroll
  for (int j = 0; j < 7; ++j) {
    const int col = j * 16 + lr;
    if (col < C) {
      const float br = b_ro[col];
#pragma unroll
      for (int i = 0; i < 2; ++i)
#pragma unroll
        for (int reg = 0; reg < 4; ++reg) {
          long m = mb + w * 32 + i * 16 + lq * 4 + reg;
          lseq[m * C + col] = fmaf(acc[i][j][reg], SB, br);
        }
    }
  }
}

// ---------------------------------------------------------------------------
// Per-row ACT chain: reads halt_seq (already in out), writes step_w + stats.
__global__ void k_act(const float* __restrict__ out_halt, float* __restrict__ swb,
                      float* __restrict__ nupb, float* __restrict__ remb) {
  const long b = (long)blockIdx.x * 256 + threadIdx.x;
  float cum = 0.f, rem = 0.f, nu = 0.f;
#pragma unroll
  for (int t = 0; t < T; ++t) {
    float halt = out_halt[b * T + t];
    float still = (cum < 0.99f) ? 1.f : 0.f;
    float nh = halt * still;
    float would = ((cum + nh) > 0.99f) ? 1.f : 0.f;
    float rema = (1.f - cum) * would * still;
    float swv = nh * (1.f - would) + rema;
    cum += swv; rem += rema; nu += still;
    swb[b * T + t] = swv;
  }
  nupb[b] = nu; remb[b] = rem;
}

// ---------------------------------------------------------------------------
__global__ void k_logits(const float* __restrict__ lseq, const float* __restrict__ swb,
                         const float* __restrict__ b_ro, const float* __restrict__ nupb,
                         float* __restrict__ out) {
  const long b = blockIdx.x;
  const int tid = threadIdx.x;
  if (tid < C) {
    float br = b_ro[tid];
    float s = br;
#pragma unroll
    for (int t = 0; t < T; ++t) {
      float sw = swb[b * T + t];
      s = fmaf(sw, lseq[(b * T + t) * C + tid] - br, s);
    }
    out[OUT_LOGITS + b * C + tid] = s;
  } else if (tid == C) {
    out[OUT_NUP + b] = nupb[b];
  }
}

// ---------------------------------------------------------------------------
__global__ void k_ponder(const float* __restrict__ nupb, const float* __restrict__ remb,
                         float* __restrict__ out) {
  __shared__ float sm[4];
  float s = 0.f;
  for (int i = threadIdx.x; i < B; i += 256) s += nupb[i] + remb[i];
#pragma unroll
  for (int m = 1; m < 64; m <<= 1) s += __shfl_xor(s, m, 64);
  int w = threadIdx.x >> 6;
  if ((threadIdx.x & 63) == 0) sm[w] = s;
  __syncthreads();
  if (threadIdx.x == 0)
    out[OUT_PONDER] = (sm[0] + sm[1] + sm[2] + sm[3]) * (1.f / (float)B);
}

// ---------------------------------------------------------------------------
extern "C" void kernel_launch(void* const* d_in, const int* in_sizes, int n_in,
                              void* d_out, int out_size, void* d_ws, size_t ws_size,
                              hipStream_t stream) {
  const float* x      = (const float*)d_in[0];
  const float* W_ih   = (const float*)d_in[1];
  const float* W_hh   = (const float*)d_in[2];
  const float* b_ih   = (const float*)d_in[3];
  const float* b_hh   = (const float*)d_in[4];
  const float* W_halt = (const float*)d_in[5];
  const float* b_halt = (const float*)d_in[6];
  const float* W_ro   = (const float*)d_in[7];
  const float* b_ro   = (const float*)d_in[8];
  float* out = (float*)d_out;
  float* ws  = (float*)d_ws;

  float* xp        = ws + WS_XP;
  _Float16* w16    = (_Float16*)(ws + WS_W16);
  _Float16* wih16  = w16;
  _Float16* whh16  = w16 + 2 * NIH;
  _Float16* waug16 = w16 + 2 * (NIH + NHH);
  float* swb  = ws + WS_HL;
  float* hp4  = ws + WS_HP4;
  float* nupb = ws + WS_NUPB;
  float* remb = ws + WS_REMB;

  k_prep<<<(int)((NIH + 255) / 256), 256, 0, stream>>>(W_ih, W_hh, W_ro, W_halt, w16);
  k_xproj<<<2048, 256, 0, stream>>>(x, wih16, b_ih, xp);
  for (int t = 0; t < T; ++t) {
    k_gru<<<2048, 256, 0, stream>>>(whh16, xp, b_hh, W_halt, out, hp4, t);
    k_sumhp<<<B / 256, 256, 0, stream>>>(hp4, b_halt, out, t);
  }
  k_lseq<<<(B * T) / 128, 256, 0, stream>>>(out + OUT_HSEQ, waug16, b_ro, out + OUT_LSEQ);
  k_act<<<B / 256, 256, 0, stream>>>(out + OUT_HALT, swb, nupb, remb);
  k_logits<<<B, 128, 0, stream>>>(out + OUT_LSEQ, swb, b_ro, nupb, out);
  k_ponder<<<1, 256, 0, stream>>>(nupb, remb, out);
}

// Round 5
// 2324.073 us; speedup vs baseline: 1.4160x; 1.4160x over previous
//
#include <hip/hip_runtime.h>
#include <cmath>

// ---------------------------------------------------------------------------
// ACT classifier (B=65536, D=512, H=256, C=100, T=10).
// Round 5 = round 3 (f16 2-split MFMA, 2^8 pre-scale, fp32-exact halt path,
// __launch_bounds__(256,2) which caps VGPR at 256 — round 4 proved removing
// it regresses) + two changes:
//  1. B-staging via __builtin_amdgcn_global_load_lds(16B): kills the
//     global->VGPR->ds_write round trip (6 b128 LDS-writes/wave/kc) in
//     k_xproj/k_gru/k_lseq. Bs layout de-padded to linear stride-32
//     (bank-uniform for the b128 fragment reads).
//  2. k_sumhp folded into k_act (hp4 gains a T dimension): 10 fewer
//     serializing launches.
// Staged bytes are bit-identical to round 3 -> halts bit-identical.
// ---------------------------------------------------------------------------

namespace {
constexpr int B = 65536, D = 512, H = 256, C = 100, T = 10;

// output layout (flat float elements, reference return order)
constexpr long OUT_LOGITS = 0;
constexpr long OUT_PONDER = (long)B * C;
constexpr long OUT_NUP    = OUT_PONDER + 1;
constexpr long OUT_HSEQ   = OUT_NUP + B;
constexpr long OUT_HALT   = OUT_HSEQ + (long)B * T * H;
constexpr long OUT_LSEQ   = OUT_HALT + (long)B * T;

// weight plane sizes (elements)
constexpr long NIH  = 768L * D;   // 393216
constexpr long NHH  = 768L * H;   // 196608
constexpr long NAUG = 112L * H;   // 28672

// workspace layout (float units)
constexpr long WS_XP   = 0;                          // x_proj [B][768] f32
constexpr long WS_W16  = WS_XP + (long)B * 768;      // f16 planes (2x each W)
constexpr long W_HALV  = 2 * (NIH + NHH + NAUG);
constexpr long WS_HL   = WS_W16 + (W_HALV + 1) / 2;  // step_w [B][T]
constexpr long WS_HP4  = WS_HL + (long)B * T;        // halt partials [T][4][B]
constexpr long WS_NUPB = WS_HP4 + 4L * B * T;
constexpr long WS_REMB = WS_NUPB + B;

constexpr float SC = 256.f;            // operand pre-scale 2^8
constexpr float SB = 1.f / 65536.f;    // product scale-back 2^-16 (exact)
} // namespace

typedef __attribute__((ext_vector_type(8))) _Float16 h8;
typedef __attribute__((ext_vector_type(4))) _Float16 h4;
typedef __attribute__((ext_vector_type(4))) float f4;

#define MFMA16(A, Bo, Cc) __builtin_amdgcn_mfma_f32_16x16x32_f16(A, Bo, Cc, 0, 0, 0)
// 3-product 2-split accumulate, smallest first
#define PROD3(a, Ah, Al, Bh, Bl)                                               \
  a = MFMA16(Al, Bh, a);                                                       \
  a = MFMA16(Ah, Bl, a);                                                       \
  a = MFMA16(Ah, Bh, a);

__device__ __forceinline__ float sigmoidf_(float x) {
  if (x >= 0.f) { return 1.f / (1.f + expf(-x)); }
  float e = expf(x);
  return e / (1.f + e);
}

// async global->LDS DMA, 16 B per lane; lds base must be wave-uniform, fills
// base + lane*16 linearly.
__device__ __forceinline__ void gload_lds16(const _Float16* g, _Float16* l) {
  __builtin_amdgcn_global_load_lds(
      (const __attribute__((address_space(1))) unsigned int*)g,
      (__attribute__((address_space(3))) unsigned int*)l, 16, 0, 0);
}

// ---------------------------------------------------------------------------
// split weights (pre-scaled by 2^8) into f16 hi/lo planes
__global__ void k_prep(const float* __restrict__ wih_s, const float* __restrict__ whh_s,
                       const float* __restrict__ wro, const float* __restrict__ whalt,
                       _Float16* __restrict__ wr) {
  long idx = (long)blockIdx.x * 256 + threadIdx.x;
  if (idx < NIH) {
    float xs = wih_s[idx] * SC;
    _Float16 h = (_Float16)xs;
    _Float16 l = (_Float16)(xs - (float)h);
    wr[idx] = h; wr[NIH + idx] = l;
  }
  if (idx < NHH) {
    float xs = whh_s[idx] * SC;
    _Float16 h = (_Float16)xs;
    _Float16 l = (_Float16)(xs - (float)h);
    long b = 2 * NIH;
    wr[b + idx] = h; wr[b + NHH + idx] = l;
  }
  if (idx < NAUG) {
    int row = (int)(idx >> 8), k = (int)(idx & 255);
    float x = (row < C) ? wro[row * 256 + k] : ((row == C) ? whalt[k] : 0.f);
    float xs = x * SC;
    _Float16 h = (_Float16)xs;
    _Float16 l = (_Float16)(xs - (float)h);
    long b = 2 * (NIH + NHH);
    wr[b + idx] = h; wr[b + NAUG + idx] = l;
  }
}

// stage 16 fp32 elems (scaled) as f16 hi/lo into LDS at row*40+kk0
__device__ __forceinline__ void stageA16(const float* __restrict__ src,
                                         _Float16* As0, _Float16* As1,
                                         int o) {
#pragma unroll
  for (int i = 0; i < 4; ++i) {
    float4 v = ((const float4*)src)[i];
    float vv[4] = {v.x, v.y, v.z, v.w};
    h4 hh, ll;
#pragma unroll
    for (int c = 0; c < 4; ++c) {
      float sv = vv[c] * SC;
      _Float16 h = (_Float16)sv;
      hh[c] = h;
      ll[c] = (_Float16)(sv - (float)h);
    }
    *(h4*)&As0[o + i * 4] = hh;
    *(h4*)&As1[o + i * 4] = ll;
  }
}

// ---------------------------------------------------------------------------
// xp = x @ W_ih^T + b_ih.  Grid 2048 (XCD-swizzled: 512 row-tiles x 4 strips).
__global__ __launch_bounds__(256, 2) void k_xproj(
    const float* __restrict__ x, const _Float16* __restrict__ wih,
    const float* __restrict__ b_ih, float* __restrict__ xp) {
  __shared__ __align__(16) _Float16 As0[128 * 40], As1[128 * 40];
  __shared__ __align__(16) _Float16 Bs[2][192 * 32];
  const int tid = threadIdx.x;
  const int w = tid >> 6, l = tid & 63;
  const int lr = l & 15, lq = l >> 4;
  const int bid = blockIdx.x;
  const int gid = (bid & 7) * 256 + (bid >> 3);   // XCD-contiguous
  const int c0 = (gid & 3) * 64;
  const int rb = (gid >> 2) * 128;

  f4 acc[8][3];
#pragma unroll
  for (int i = 0; i < 8; ++i)
#pragma unroll
    for (int g = 0; g < 3; ++g) acc[i][g] = (f4)0.f;

  for (int kc = 0; kc < 16; ++kc) {
    const int k0 = kc * 32;
    __syncthreads();
    {  // stage A (x rows, scaled split)
      const int row = tid >> 1, kk0 = (tid & 1) * 16;
      stageA16(x + (long)(rb + row) * D + k0 + kk0, As0, As1, row * 40 + kk0);
    }
    // stage B via async DMA: 2 planes x 12 KB, 6 x 1KB chunks per wave
#pragma unroll
    for (int j = 0; j < 6; ++j) {
      int chunk = w * 6 + j;           // 0..23
      int plane = chunk / 12;
      int rem = chunk - plane * 12;
      int scol = rem * 16 + (l >> 2);
      int kq = l & 3;
      int gcol = (scol >> 6) * 256 + c0 + (scol & 63);
      gload_lds16(wih + (long)plane * NIH + (long)gcol * D + k0 + kq * 8,
                  &Bs[plane][rem * 512]);
    }
    __syncthreads();
    h8 Bh[3], Bl[3];
#pragma unroll
    for (int g = 0; g < 3; ++g) {
      Bh[g] = *(const h8*)&Bs[0][(g * 64 + w * 16 + lr) * 32 + lq * 8];
      Bl[g] = *(const h8*)&Bs[1][(g * 64 + w * 16 + lr) * 32 + lq * 8];
    }
#pragma unroll
    for (int i = 0; i < 8; ++i) {
      h8 Ah = *(const h8*)&As0[(i * 16 + lr) * 40 + lq * 8];
      h8 Al = *(const h8*)&As1[(i * 16 + lr) * 40 + lq * 8];
#pragma unroll
      for (int g = 0; g < 3; ++g) { PROD3(acc[i][g], Ah, Al, Bh[g], Bl[g]); }
    }
  }
  const int ch = c0 + w * 16 + lr;
  float bi[3] = {b_ih[ch], b_ih[256 + ch], b_ih[512 + ch]};
#pragma unroll
  for (int i = 0; i < 8; ++i)
#pragma unroll
    for (int g = 0; g < 3; ++g)
#pragma unroll
      for (int reg = 0; reg < 4; ++reg) {
        long row = rb + i * 16 + lq * 4 + reg;
        xp[row * 768 + g * 256 + ch] = fmaf(acc[i][g][reg], SB, bi[g]);
      }
}

// ---------------------------------------------------------------------------
// One GRU step + fp32-exact halt partial dot per 64-col strip.
__global__ __launch_bounds__(256, 2) void k_gru(
    const _Float16* __restrict__ whh, const float* __restrict__ xp,
    const float* __restrict__ b_hh, const float* __restrict__ w_halt,
    float* __restrict__ out, float* __restrict__ hp4, int t) {
  __shared__ __align__(16) _Float16 As0[128 * 40], As1[128 * 40];
  __shared__ __align__(16) _Float16 Bs[2][192 * 32];
  __shared__ float lds_hp[128][4];
  const int tid = threadIdx.x;
  const int w = tid >> 6, l = tid & 63;
  const int lr = l & 15, lq = l >> 4;
  const int bid = blockIdx.x;
  const int gid = (bid & 7) * 256 + (bid >> 3);
  const int strip = gid & 3;
  const int c0 = strip * 64;
  const int rb = (gid >> 2) * 128;

  f4 acc[8][3];
#pragma unroll
  for (int i = 0; i < 8; ++i)
#pragma unroll
    for (int g = 0; g < 3; ++g) acc[i][g] = (f4)0.f;

  if (t > 0) {
    for (int kc = 0; kc < 8; ++kc) {
      const int k0 = kc * 32;
      __syncthreads();
      {  // stage A = h_{t-1}
        const int row = tid >> 1, kk0 = (tid & 1) * 16;
        stageA16(out + OUT_HSEQ + (long)(rb + row) * (T * H) + (long)(t - 1) * H + k0 + kk0,
                 As0, As1, row * 40 + kk0);
      }
      // stage B via async DMA
#pragma unroll
      for (int j = 0; j < 6; ++j) {
        int chunk = w * 6 + j;
        int plane = chunk / 12;
        int rem = chunk - plane * 12;
        int scol = rem * 16 + (l >> 2);
        int kq = l & 3;
        int gcol = (scol >> 6) * 256 + c0 + (scol & 63);
        gload_lds16(whh + (long)plane * NHH + (long)gcol * H + k0 + kq * 8,
                    &Bs[plane][rem * 512]);
      }
      __syncthreads();
      h8 Bh[3], Bl[3];
#pragma unroll
      for (int g = 0; g < 3; ++g) {
        Bh[g] = *(const h8*)&Bs[0][(g * 64 + w * 16 + lr) * 32 + lq * 8];
        Bl[g] = *(const h8*)&Bs[1][(g * 64 + w * 16 + lr) * 32 + lq * 8];
      }
#pragma unroll
      for (int i = 0; i < 8; ++i) {
        h8 Ah = *(const h8*)&As0[(i * 16 + lr) * 40 + lq * 8];
        h8 Al = *(const h8*)&As1[(i * 16 + lr) * 40 + lq * 8];
#pragma unroll
        for (int g = 0; g < 3; ++g) { PROD3(acc[i][g], Ah, Al, Bh[g], Bl[g]); }
      }
    }
  }

  // epilogue: gates + h_new + halt partial
  const int ch = c0 + w * 16 + lr;
  const float bhr = b_hh[ch], bhz = b_hh[256 + ch], bhn = b_hh[512 + ch];
  const float whv = w_halt[ch];
#pragma unroll
  for (int i = 0; i < 8; ++i)
#pragma unroll
    for (int reg = 0; reg < 4; ++reg) {
      const int rloc = i * 16 + lq * 4 + reg;
      const long row = rb + rloc;
      float xr = xp[row * 768 + ch];
      float xz = xp[row * 768 + 256 + ch];
      float xn = xp[row * 768 + 512 + ch];
      float ho = (t > 0) ? out[OUT_HSEQ + row * (T * H) + (long)(t - 1) * H + ch] : 0.f;
      float rr = sigmoidf_(xr + fmaf(acc[i][0][reg], SB, bhr));
      float zz = sigmoidf_(xz + fmaf(acc[i][1][reg], SB, bhz));
      float nn = tanhf(xn + rr * fmaf(acc[i][2][reg], SB, bhn));
      float hv = (1.f - zz) * nn + zz * ho;
      out[OUT_HSEQ + row * (T * H) + (long)t * H + ch] = hv;
      // halt partial over this wave's 16 cols (fp32 shuffle tree)
      float p = hv * whv;
#pragma unroll
      for (int m = 1; m < 16; m <<= 1) p += __shfl_xor(p, m, 64);
      if (lr == 0) lds_hp[rloc][w] = p;
    }
  __syncthreads();
  if (tid < 128)
    hp4[((long)t * 4 + strip) * B + rb + tid] =
        ((lds_hp[tid][0] + lds_hp[tid][1]) + (lds_hp[tid][2] + lds_hp[tid][3]));
}

// ---------------------------------------------------------------------------
// Readout: [B*T,256] x [256,112] single-product f16 (cols 0..99 kept).
__global__ __launch_bounds__(256, 4) void k_lseq(
    const float* __restrict__ hseq, const _Float16* __restrict__ waug,
    const float* __restrict__ b_ro, float* __restrict__ lseq) {
  __shared__ __align__(16) _Float16 As0[128 * 40];
  __shared__ __align__(16) _Float16 Bs[112 * 32];
  const int tid = threadIdx.x;
  const int w = tid >> 6, l = tid & 63;
  const int lr = l & 15, lq = l >> 4;
  const long mb = (long)blockIdx.x * 128;

  f4 acc[2][7];
#pragma unroll
  for (int i = 0; i < 2; ++i)
#pragma unroll
    for (int j = 0; j < 7; ++j) acc[i][j] = (f4)0.f;

  for (int kc = 0; kc < 8; ++kc) {
    const int k0 = kc * 32;
    __syncthreads();
    {  // stage A hi-plane only
      const int row = tid >> 1, kk0 = (tid & 1) * 16;
      const float* src = hseq + (mb + row) * H + k0 + kk0;
      const int o = row * 40 + kk0;
#pragma unroll
      for (int i = 0; i < 4; ++i) {
        float4 v = ((const float4*)src)[i];
        h4 hh;
        hh[0] = (_Float16)(v.x * SC); hh[1] = (_Float16)(v.y * SC);
        hh[2] = (_Float16)(v.z * SC); hh[3] = (_Float16)(v.w * SC);
        *(h4*)&As0[o + i * 4] = hh;
      }
    }
    // stage B hi-plane via async DMA: 7 x 1KB chunks
#pragma unroll
    for (int j = 0; j < 2; ++j) {
      int chunk = w + j * 4;
      if (chunk < 7) {
        int scol = chunk * 16 + (l >> 2);
        int kq = l & 3;
        gload_lds16(waug + (long)scol * H + k0 + kq * 8, &Bs[chunk * 512]);
      }
    }
    __syncthreads();
    h8 Af[2];
#pragma unroll
    for (int i = 0; i < 2; ++i)
      Af[i] = *(const h8*)&As0[(w * 32 + i * 16 + lr) * 40 + lq * 8];
#pragma unroll
    for (int j = 0; j < 7; ++j) {
      h8 Bf = *(const h8*)&Bs[(j * 16 + lr) * 32 + lq * 8];
#pragma unroll
      for (int i = 0; i < 2; ++i) acc[i][j] = MFMA16(Af[i], Bf, acc[i][j]);
    }
  }
#pragma unroll
  for (int j = 0; j < 7; ++j) {
    const int col = j * 16 + lr;
    if (col < C) {
      const float br = b_ro[col];
#pragma unroll
      for (int i = 0; i < 2; ++i)
#pragma unroll
        for (int reg = 0; reg < 4; ++reg) {
          long m = mb + w * 32 + i * 16 + lq * 4 + reg;
          lseq[m * C + col] = fmaf(acc[i][j][reg], SB, br);
        }
    }
  }
}

// ---------------------------------------------------------------------------
// Per-row: halt[t] = sigmoid(b_halt + 4 strip partials), then ACT chain.
// Summation order matches round-3 k_sumhp exactly (bit-identical halts).
__global__ void k_act(const float* __restrict__ hp4, const float* __restrict__ b_halt,
                      float* __restrict__ out, float* __restrict__ swb,
                      float* __restrict__ nupb, float* __restrict__ remb) {
  const long b = (long)blockIdx.x * 256 + threadIdx.x;
  const float bh = b_halt[0];
  float cum = 0.f, rem = 0.f, nu = 0.f;
#pragma unroll
  for (int t = 0; t < T; ++t) {
    float v = bh + hp4[((long)t * 4 + 0) * B + b] + hp4[((long)t * 4 + 1) * B + b] +
              hp4[((long)t * 4 + 2) * B + b] + hp4[((long)t * 4 + 3) * B + b];
    float halt = sigmoidf_(v);
    out[OUT_HALT + b * T + t] = halt;
    float still = (cum < 0.99f) ? 1.f : 0.f;
    float nh = halt * still;
    float would = ((cum + nh) > 0.99f) ? 1.f : 0.f;
    float rema = (1.f - cum) * would * still;
    float swv = nh * (1.f - would) + rema;
    cum += swv; rem += rema; nu += still;
    swb[b * T + t] = swv;
  }
  nupb[b] = nu; remb[b] = rem;
}

// ---------------------------------------------------------------------------
__global__ void k_logits(const float* __restrict__ lseq, const float* __restrict__ swb,
                         const float* __restrict__ b_ro, const float* __restrict__ nupb,
                         float* __restrict__ out) {
  const long b = blockIdx.x;
  const int tid = threadIdx.x;
  if (tid < C) {
    float br = b_ro[tid];
    float s = br;
#pragma unroll
    for (int t = 0; t < T; ++t) {
      float sw = swb[b * T + t];
      s = fmaf(sw, lseq[(b * T + t) * C + tid] - br, s);
    }
    out[OUT_LOGITS + b * C + tid] = s;
  } else if (tid == C) {
    out[OUT_NUP + b] = nupb[b];
  }
}

// ---------------------------------------------------------------------------
__global__ void k_ponder(const float* __restrict__ nupb, const float* __restrict__ remb,
                         float* __restrict__ out) {
  __shared__ float sm[4];
  float s = 0.f;
  for (int i = threadIdx.x; i < B; i += 256) s += nupb[i] + remb[i];
#pragma unroll
  for (int m = 1; m < 64; m <<= 1) s += __shfl_xor(s, m, 64);
  int w = threadIdx.x >> 6;
  if ((threadIdx.x & 63) == 0) sm[w] = s;
  __syncthreads();
  if (threadIdx.x == 0)
    out[OUT_PONDER] = (sm[0] + sm[1] + sm[2] + sm[3]) * (1.f / (float)B);
}

// ---------------------------------------------------------------------------
extern "C" void kernel_launch(void* const* d_in, const int* in_sizes, int n_in,
                              void* d_out, int out_size, void* d_ws, size_t ws_size,
                              hipStream_t stream) {
  const float* x      = (const float*)d_in[0];
  const float* W_ih   = (const float*)d_in[1];
  const float* W_hh   = (const float*)d_in[2];
  const float* b_ih   = (const float*)d_in[3];
  const float* b_hh   = (const float*)d_in[4];
  const float* W_halt = (const float*)d_in[5];
  const float* b_halt = (const float*)d_in[6];
  const float* W_ro   = (const float*)d_in[7];
  const float* b_ro   = (const float*)d_in[8];
  float* out = (float*)d_out;
  float* ws  = (float*)d_ws;

  float* xp        = ws + WS_XP;
  _Float16* w16    = (_Float16*)(ws + WS_W16);
  _Float16* wih16  = w16;
  _Float16* whh16  = w16 + 2 * NIH;
  _Float16* waug16 = w16 + 2 * (NIH + NHH);
  float* swb  = ws + WS_HL;
  float* hp4  = ws + WS_HP4;
  float* nupb = ws + WS_NUPB;
  float* remb = ws + WS_REMB;

  k_prep<<<(int)((NIH + 255) / 256), 256, 0, stream>>>(W_ih, W_hh, W_ro, W_halt, w16);
  k_xproj<<<2048, 256, 0, stream>>>(x, wih16, b_ih, xp);
  for (int t = 0; t < T; ++t)
    k_gru<<<2048, 256, 0, stream>>>(whh16, xp, b_hh, W_halt, out, hp4, t);
  k_lseq<<<(B * T) / 128, 256, 0, stream>>>(out + OUT_HSEQ, waug16, b_ro, out + OUT_LSEQ);
  k_act<<<B / 256, 256, 0, stream>>>(hp4, b_halt, out, swb, nupb, remb);
  k_logits<<<B, 128, 0, stream>>>(out + OUT_LSEQ, swb, b_ro, nupb, out);
  k_ponder<<<1, 256, 0, stream>>>(nupb, remb, out);
}

// Round 6
// 2311.257 us; speedup vs baseline: 1.4239x; 1.0055x over previous
//
#include <hip/hip_runtime.h>
#include <cmath>

// ---------------------------------------------------------------------------
// ACT classifier (B=65536, D=512, H=256, C=100, T=10).
// Round 6 = round 5 + h16-plane carrier for the GRU recurrence:
//   k_gru's epilogue writes h_new's f16 hi/lo planes PRE-TILED in the exact
//   LDS image the next step's A-stage needs ([tile][kc][plane][r][kk], 8KB
//   contiguous per (kc,plane)). A-staging becomes pure global_load_lds DMA —
//   no fp32 re-read, no per-strip re-conversion (was 4x duplicated), no LDS
//   writes in the hot loop. Staged bytes bit-identical to round 5 (same
//   hv*SC -> f16 hi/lo formulas on the same fp32 value) -> halts identical.
//   h16 aliases d_out's LSEQ region (only written later by k_lseq).
// Round-4 lesson kept: __launch_bounds__(256,2) (VGPR cap 256) stays.
// ---------------------------------------------------------------------------

namespace {
constexpr int B = 65536, D = 512, H = 256, C = 100, T = 10;

// output layout (flat float elements, reference return order)
constexpr long OUT_LOGITS = 0;
constexpr long OUT_PONDER = (long)B * C;
constexpr long OUT_NUP    = OUT_PONDER + 1;
constexpr long OUT_HSEQ   = OUT_NUP + B;
constexpr long OUT_HALT   = OUT_HSEQ + (long)B * T * H;
constexpr long OUT_LSEQ   = OUT_HALT + (long)B * T;
// h16 carrier aliases the LSEQ region (16B-aligned float offset)
constexpr long OUT_H16    = (OUT_LSEQ + 3) & ~3L;

// weight plane sizes (elements)
constexpr long NIH  = 768L * D;   // 393216
constexpr long NHH  = 768L * H;   // 196608
constexpr long NAUG = 112L * H;   // 28672

// workspace layout (float units)
constexpr long WS_XP   = 0;                          // x_proj [B][768] f32
constexpr long WS_W16  = WS_XP + (long)B * 768;      // f16 planes (2x each W)
constexpr long W_HALV  = 2 * (NIH + NHH + NAUG);
constexpr long WS_HL   = WS_W16 + (W_HALV + 1) / 2;  // step_w [B][T]
constexpr long WS_HP4  = WS_HL + (long)B * T;        // halt partials [T][4][B]
constexpr long WS_NUPB = WS_HP4 + 4L * B * T;
constexpr long WS_REMB = WS_NUPB + B;

constexpr float SC = 256.f;            // operand pre-scale 2^8
constexpr float SB = 1.f / 65536.f;    // product scale-back 2^-16 (exact)
} // namespace

typedef __attribute__((ext_vector_type(8))) _Float16 h8;
typedef __attribute__((ext_vector_type(4))) _Float16 h4;
typedef __attribute__((ext_vector_type(4))) float f4;

#define MFMA16(A, Bo, Cc) __builtin_amdgcn_mfma_f32_16x16x32_f16(A, Bo, Cc, 0, 0, 0)
// 3-product 2-split accumulate, smallest first
#define PROD3(a, Ah, Al, Bh, Bl)                                               \
  a = MFMA16(Al, Bh, a);                                                       \
  a = MFMA16(Ah, Bl, a);                                                       \
  a = MFMA16(Ah, Bh, a);

__device__ __forceinline__ float sigmoidf_(float x) {
  if (x >= 0.f) { return 1.f / (1.f + expf(-x)); }
  float e = expf(x);
  return e / (1.f + e);
}

// async global->LDS DMA, 16 B per lane; lds base wave-uniform, fills
// base + lane*16 linearly; global src is per-lane.
__device__ __forceinline__ void gload_lds16(const _Float16* g, _Float16* l) {
  __builtin_amdgcn_global_load_lds(
      (const __attribute__((address_space(1))) unsigned int*)g,
      (__attribute__((address_space(3))) unsigned int*)l, 16, 0, 0);
}

// ---------------------------------------------------------------------------
// split weights (pre-scaled by 2^8) into f16 hi/lo planes
__global__ void k_prep(const float* __restrict__ wih_s, const float* __restrict__ whh_s,
                       const float* __restrict__ wro, const float* __restrict__ whalt,
                       _Float16* __restrict__ wr) {
  long idx = (long)blockIdx.x * 256 + threadIdx.x;
  if (idx < NIH) {
    float xs = wih_s[idx] * SC;
    _Float16 h = (_Float16)xs;
    _Float16 l = (_Float16)(xs - (float)h);
    wr[idx] = h; wr[NIH + idx] = l;
  }
  if (idx < NHH) {
    float xs = whh_s[idx] * SC;
    _Float16 h = (_Float16)xs;
    _Float16 l = (_Float16)(xs - (float)h);
    long b = 2 * NIH;
    wr[b + idx] = h; wr[b + NHH + idx] = l;
  }
  if (idx < NAUG) {
    int row = (int)(idx >> 8), k = (int)(idx & 255);
    float x = (row < C) ? wro[row * 256 + k] : ((row == C) ? whalt[k] : 0.f);
    float xs = x * SC;
    _Float16 h = (_Float16)xs;
    _Float16 l = (_Float16)(xs - (float)h);
    long b = 2 * (NIH + NHH);
    wr[b + idx] = h; wr[b + NAUG + idx] = l;
  }
}

// stage 16 fp32 elems (scaled) as f16 hi/lo into LDS at row*40+kk0
__device__ __forceinline__ void stageA16(const float* __restrict__ src,
                                         _Float16* As0, _Float16* As1,
                                         int o) {
#pragma unroll
  for (int i = 0; i < 4; ++i) {
    float4 v = ((const float4*)src)[i];
    float vv[4] = {v.x, v.y, v.z, v.w};
    h4 hh, ll;
#pragma unroll
    for (int c = 0; c < 4; ++c) {
      float sv = vv[c] * SC;
      _Float16 h = (_Float16)sv;
      hh[c] = h;
      ll[c] = (_Float16)(sv - (float)h);
    }
    *(h4*)&As0[o + i * 4] = hh;
    *(h4*)&As1[o + i * 4] = ll;
  }
}

// ---------------------------------------------------------------------------
// xp = x @ W_ih^T + b_ih.  Grid 2048 (XCD-swizzled: 512 row-tiles x 4 strips).
__global__ __launch_bounds__(256, 2) void k_xproj(
    const float* __restrict__ x, const _Float16* __restrict__ wih,
    const float* __restrict__ b_ih, float* __restrict__ xp) {
  __shared__ __align__(16) _Float16 As0[128 * 40], As1[128 * 40];
  __shared__ __align__(16) _Float16 Bs[2][192 * 32];
  const int tid = threadIdx.x;
  const int w = tid >> 6, l = tid & 63;
  const int lr = l & 15, lq = l >> 4;
  const int bid = blockIdx.x;
  const int gid = (bid & 7) * 256 + (bid >> 3);   // XCD-contiguous
  const int c0 = (gid & 3) * 64;
  const int rb = (gid >> 2) * 128;

  f4 acc[8][3];
#pragma unroll
  for (int i = 0; i < 8; ++i)
#pragma unroll
    for (int g = 0; g < 3; ++g) acc[i][g] = (f4)0.f;

  for (int kc = 0; kc < 16; ++kc) {
    const int k0 = kc * 32;
    __syncthreads();
    {  // stage A (x rows, scaled split)
      const int row = tid >> 1, kk0 = (tid & 1) * 16;
      stageA16(x + (long)(rb + row) * D + k0 + kk0, As0, As1, row * 40 + kk0);
    }
    // stage B via async DMA: 2 planes x 12 KB, 6 x 1KB chunks per wave
#pragma unroll
    for (int j = 0; j < 6; ++j) {
      int chunk = w * 6 + j;           // 0..23
      int plane = chunk / 12;
      int rem = chunk - plane * 12;
      int scol = rem * 16 + (l >> 2);
      int kq = l & 3;
      int gcol = (scol >> 6) * 256 + c0 + (scol & 63);
      gload_lds16(wih + (long)plane * NIH + (long)gcol * D + k0 + kq * 8,
                  &Bs[plane][rem * 512]);
    }
    __syncthreads();
    h8 Bh[3], Bl[3];
#pragma unroll
    for (int g = 0; g < 3; ++g) {
      Bh[g] = *(const h8*)&Bs[0][(g * 64 + w * 16 + lr) * 32 + lq * 8];
      Bl[g] = *(const h8*)&Bs[1][(g * 64 + w * 16 + lr) * 32 + lq * 8];
    }
#pragma unroll
    for (int i = 0; i < 8; ++i) {
      h8 Ah = *(const h8*)&As0[(i * 16 + lr) * 40 + lq * 8];
      h8 Al = *(const h8*)&As1[(i * 16 + lr) * 40 + lq * 8];
#pragma unroll
      for (int g = 0; g < 3; ++g) { PROD3(acc[i][g], Ah, Al, Bh[g], Bl[g]); }
    }
  }
  const int ch = c0 + w * 16 + lr;
  float bi[3] = {b_ih[ch], b_ih[256 + ch], b_ih[512 + ch]};
#pragma unroll
  for (int i = 0; i < 8; ++i)
#pragma unroll
    for (int g = 0; g < 3; ++g)
#pragma unroll
      for (int reg = 0; reg < 4; ++reg) {
        long row = rb + i * 16 + lq * 4 + reg;
        xp[row * 768 + g * 256 + ch] = fmaf(acc[i][g][reg], SB, bi[g]);
      }
}

// ---------------------------------------------------------------------------
// One GRU step + fp32-exact halt partial dot per 64-col strip.
// A-operand comes pre-split/pre-tiled from h16 (written by previous step's
// epilogue): h16[tile rb/128][kc][plane][r 0..127][kk 0..31], halves.
__global__ __launch_bounds__(256, 2) void k_gru(
    const _Float16* __restrict__ whh, const float* __restrict__ xp,
    const float* __restrict__ b_hh, const float* __restrict__ w_halt,
    float* __restrict__ out, _Float16* __restrict__ h16,
    float* __restrict__ hp4, int t) {
  __shared__ __align__(16) _Float16 As[2][128 * 32];
  __shared__ __align__(16) _Float16 Bs[2][192 * 32];
  __shared__ float lds_hp[128][4];
  const int tid = threadIdx.x;
  const int w = tid >> 6, l = tid & 63;
  const int lr = l & 15, lq = l >> 4;
  const int bid = blockIdx.x;
  const int gid = (bid & 7) * 256 + (bid >> 3);
  const int strip = gid & 3;
  const int c0 = strip * 64;
  const int rb = (gid >> 2) * 128;
  const long tilebase = (long)(rb >> 7) * 65536;   // 8 kc * 2 planes * 4096

  f4 acc[8][3];
#pragma unroll
  for (int i = 0; i < 8; ++i)
#pragma unroll
    for (int g = 0; g < 3; ++g) acc[i][g] = (f4)0.f;

  if (t > 0) {
    for (int kc = 0; kc < 8; ++kc) {
      const int k0 = kc * 32;
      __syncthreads();
      // stage A via DMA: 2 planes x 8KB = 16 chunks of 1KB; 4 per wave
#pragma unroll
      for (int j = 0; j < 4; ++j) {
        int c8 = w * 4 + j;          // 0..15
        int plane = c8 >> 3;
        int c = c8 & 7;
        gload_lds16(h16 + tilebase + (long)kc * 8192 + plane * 4096 + c * 512 + l * 8,
                    &As[plane][c * 512]);
      }
      // stage B via DMA
#pragma unroll
      for (int j = 0; j < 6; ++j) {
        int chunk = w * 6 + j;
        int plane = chunk / 12;
        int rem = chunk - plane * 12;
        int scol = rem * 16 + (l >> 2);
        int kq = l & 3;
        int gcol = (scol >> 6) * 256 + c0 + (scol & 63);
        gload_lds16(whh + (long)plane * NHH + (long)gcol * H + k0 + kq * 8,
                    &Bs[plane][rem * 512]);
      }
      __syncthreads();
      h8 Bh[3], Bl[3];
#pragma unroll
      for (int g = 0; g < 3; ++g) {
        Bh[g] = *(const h8*)&Bs[0][(g * 64 + w * 16 + lr) * 32 + lq * 8];
        Bl[g] = *(const h8*)&Bs[1][(g * 64 + w * 16 + lr) * 32 + lq * 8];
      }
#pragma unroll
      for (int i = 0; i < 8; ++i) {
        h8 Ah = *(const h8*)&As[0][(i * 16 + lr) * 32 + lq * 8];
        h8 Al = *(const h8*)&As[1][(i * 16 + lr) * 32 + lq * 8];
#pragma unroll
        for (int g = 0; g < 3; ++g) { PROD3(acc[i][g], Ah, Al, Bh[g], Bl[g]); }
      }
    }
  }

  // epilogue: gates + h_new + h16 planes + halt partial
  const int ch = c0 + w * 16 + lr;
  const float bhr = b_hh[ch], bhz = b_hh[256 + ch], bhn = b_hh[512 + ch];
  const float whv = w_halt[ch];
  // h16 write base for this thread's column: [tile][ch>>5][plane][r][ch&31]
  const long h16c = tilebase + (long)(ch >> 5) * 8192 + (ch & 31);
#pragma unroll
  for (int i = 0; i < 8; ++i)
#pragma unroll
    for (int reg = 0; reg < 4; ++reg) {
      const int rloc = i * 16 + lq * 4 + reg;
      const long row = rb + rloc;
      float xr = xp[row * 768 + ch];
      float xz = xp[row * 768 + 256 + ch];
      float xn = xp[row * 768 + 512 + ch];
      float ho = (t > 0) ? out[OUT_HSEQ + row * (T * H) + (long)(t - 1) * H + ch] : 0.f;
      float rr = sigmoidf_(xr + fmaf(acc[i][0][reg], SB, bhr));
      float zz = sigmoidf_(xz + fmaf(acc[i][1][reg], SB, bhz));
      float nn = tanhf(xn + rr * fmaf(acc[i][2][reg], SB, bhn));
      float hv = (1.f - zz) * nn + zz * ho;
      out[OUT_HSEQ + row * (T * H) + (long)t * H + ch] = hv;
      // pre-split/pre-tiled carrier for next step's A-DMA (same formulas as
      // round-5 stageA16 -> bit-identical staged bytes)
      float sv = hv * SC;
      _Float16 hi = (_Float16)sv;
      _Float16 lo = (_Float16)(sv - (float)hi);
      h16[h16c + (long)rloc * 32] = hi;
      h16[h16c + 4096 + (long)rloc * 32] = lo;
      // halt partial over this wave's 16 cols (fp32 shuffle tree)
      float p = hv * whv;
#pragma unroll
      for (int m = 1; m < 16; m <<= 1) p += __shfl_xor(p, m, 64);
      if (lr == 0) lds_hp[rloc][w] = p;
    }
  __syncthreads();
  if (tid < 128)
    hp4[((long)t * 4 + strip) * B + rb + tid] =
        ((lds_hp[tid][0] + lds_hp[tid][1]) + (lds_hp[tid][2] + lds_hp[tid][3]));
}

// ---------------------------------------------------------------------------
// Readout: [B*T,256] x [256,112] single-product f16 (cols 0..99 kept).
__global__ __launch_bounds__(256, 4) void k_lseq(
    const float* __restrict__ hseq, const _Float16* __restrict__ waug,
    const float* __restrict__ b_ro, float* __restrict__ lseq) {
  __shared__ __align__(16) _Float16 As0[128 * 40];
  __shared__ __align__(16) _Float16 Bs[112 * 32];
  const int tid = threadIdx.x;
  const int w = tid >> 6, l = tid & 63;
  const int lr = l & 15, lq = l >> 4;
  const long mb = (long)blockIdx.x * 128;

  f4 acc[2][7];
#pragma unroll
  for (int i = 0; i < 2; ++i)
#pragma unroll
    for (int j = 0; j < 7; ++j) acc[i][j] = (f4)0.f;

  for (int kc = 0; kc < 8; ++kc) {
    const int k0 = kc * 32;
    __syncthreads();
    {  // stage A hi-plane only
      const int row = tid >> 1, kk0 = (tid & 1) * 16;
      const float* src = hseq + (mb + row) * H + k0 + kk0;
      const int o = row * 40 + kk0;
#pragma unroll
      for (int i = 0; i < 4; ++i) {
        float4 v = ((const float4*)src)[i];
        h4 hh;
        hh[0] = (_Float16)(v.x * SC); hh[1] = (_Float16)(v.y * SC);
        hh[2] = (_Float16)(v.z * SC); hh[3] = (_Float16)(v.w * SC);
        *(h4*)&As0[o + i * 4] = hh;
      }
    }
    // stage B hi-plane via async DMA: 7 x 1KB chunks
#pragma unroll
    for (int j = 0; j < 2; ++j) {
      int chunk = w + j * 4;
      if (chunk < 7) {
        int scol = chunk * 16 + (l >> 2);
        int kq = l & 3;
        gload_lds16(waug + (long)scol * H + k0 + kq * 8, &Bs[chunk * 512]);
      }
    }
    __syncthreads();
    h8 Af[2];
#pragma unroll
    for (int i = 0; i < 2; ++i)
      Af[i] = *(const h8*)&As0[(w * 32 + i * 16 + lr) * 40 + lq * 8];
#pragma unroll
    for (int j = 0; j < 7; ++j) {
      h8 Bf = *(const h8*)&Bs[(j * 16 + lr) * 32 + lq * 8];
#pragma unroll
      for (int i = 0; i < 2; ++i) acc[i][j] = MFMA16(Af[i], Bf, acc[i][j]);
    }
  }
#pragma unroll
  for (int j = 0; j < 7; ++j) {
    const int col = j * 16 + lr;
    if (col < C) {
      const float br = b_ro[col];
#pragma unroll
      for (int i = 0; i < 2; ++i)
#pragma unroll
        for (int reg = 0; reg < 4; ++reg) {
          long m = mb + w * 32 + i * 16 + lq * 4 + reg;
          lseq[m * C + col] = fmaf(acc[i][j][reg], SB, br);
        }
    }
  }
}

// ---------------------------------------------------------------------------
// Per-row: halt[t] = sigmoid(b_halt + 4 strip partials), then ACT chain.
__global__ void k_act(const float* __restrict__ hp4, const float* __restrict__ b_halt,
                      float* __restrict__ out, float* __restrict__ swb,
                      float* __restrict__ nupb, float* __restrict__ remb) {
  const long b = (long)blockIdx.x * 256 + threadIdx.x;
  const float bh = b_halt[0];
  float cum = 0.f, rem = 0.f, nu = 0.f;
#pragma unroll
  for (int t = 0; t < T; ++t) {
    float v = bh + hp4[((long)t * 4 + 0) * B + b] + hp4[((long)t * 4 + 1) * B + b] +
              hp4[((long)t * 4 + 2) * B + b] + hp4[((long)t * 4 + 3) * B + b];
    float halt = sigmoidf_(v);
    out[OUT_HALT + b * T + t] = halt;
    float still = (cum < 0.99f) ? 1.f : 0.f;
    float nh = halt * still;
    float would = ((cum + nh) > 0.99f) ? 1.f : 0.f;
    float rema = (1.f - cum) * would * still;
    float swv = nh * (1.f - would) + rema;
    cum += swv; rem += rema; nu += still;
    swb[b * T + t] = swv;
  }
  nupb[b] = nu; remb[b] = rem;
}

// ---------------------------------------------------------------------------
__global__ void k_logits(const float* __restrict__ lseq, const float* __restrict__ swb,
                         const float* __restrict__ b_ro, const float* __restrict__ nupb,
                         float* __restrict__ out) {
  const long b = blockIdx.x;
  const int tid = threadIdx.x;
  if (tid < C) {
    float br = b_ro[tid];
    float s = br;
#pragma unroll
    for (int t = 0; t < T; ++t) {
      float sw = swb[b * T + t];
      s = fmaf(sw, lseq[(b * T + t) * C + tid] - br, s);
    }
    out[OUT_LOGITS + b * C + tid] = s;
  } else if (tid == C) {
    out[OUT_NUP + b] = nupb[b];
  }
}

// ---------------------------------------------------------------------------
__global__ void k_ponder(const float* __restrict__ nupb, const float* __restrict__ remb,
                         float* __restrict__ out) {
  __shared__ float sm[4];
  float s = 0.f;
  for (int i = threadIdx.x; i < B; i += 256) s += nupb[i] + remb[i];
#pragma unroll
  for (int m = 1; m < 64; m <<= 1) s += __shfl_xor(s, m, 64);
  int w = threadIdx.x >> 6;
  if ((threadIdx.x & 63) == 0) sm[w] = s;
  __syncthreads();
  if (threadIdx.x == 0)
    out[OUT_PONDER] = (sm[0] + sm[1] + sm[2] + sm[3]) * (1.f / (float)B);
}

// ---------------------------------------------------------------------------
extern "C" void kernel_launch(void* const* d_in, const int* in_sizes, int n_in,
                              void* d_out, int out_size, void* d_ws, size_t ws_size,
                              hipStream_t stream) {
  const float* x      = (const float*)d_in[0];
  const float* W_ih   = (const float*)d_in[1];
  const float* W_hh   = (const float*)d_in[2];
  const float* b_ih   = (const float*)d_in[3];
  const float* b_hh   = (const float*)d_in[4];
  const float* W_halt = (const float*)d_in[5];
  const float* b_halt = (const float*)d_in[6];
  const float* W_ro   = (const float*)d_in[7];
  const float* b_ro   = (const float*)d_in[8];
  float* out = (float*)d_out;
  float* ws  = (float*)d_ws;

  float* xp        = ws + WS_XP;
  _Float16* w16    = (_Float16*)(ws + WS_W16);
  _Float16* wih16  = w16;
  _Float16* whh16  = w16 + 2 * NIH;
  _Float16* waug16 = w16 + 2 * (NIH + NHH);
  float* swb  = ws + WS_HL;
  float* hp4  = ws + WS_HP4;
  float* nupb = ws + WS_NUPB;
  float* remb = ws + WS_REMB;
  _Float16* h16 = (_Float16*)(out + OUT_H16);   // transient carrier in LSEQ region

  k_prep<<<(int)((NIH + 255) / 256), 256, 0, stream>>>(W_ih, W_hh, W_ro, W_halt, w16);
  k_xproj<<<2048, 256, 0, stream>>>(x, wih16, b_ih, xp);
  for (int t = 0; t < T; ++t)
    k_gru<<<2048, 256, 0, stream>>>(whh16, xp, b_hh, W_halt, out, h16, hp4, t);
  k_lseq<<<(B * T) / 128, 256, 0, stream>>>(out + OUT_HSEQ, waug16, b_ro, out + OUT_LSEQ);
  k_act<<<B / 256, 256, 0, stream>>>(hp4, b_halt, out, swb, nupb, remb);
  k_logits<<<B, 128, 0, stream>>>(out + OUT_LSEQ, swb, b_ro, nupb, out);
  k_ponder<<<1, 256, 0, stream>>>(nupb, remb, out);
}

// Round 7
// 2239.205 us; speedup vs baseline: 1.4697x; 1.0322x over previous
//
#include <hip/hip_runtime.h>
#include <cmath>

// ---------------------------------------------------------------------------
// ACT classifier (B=65536, D=512, H=256, C=100, T=10).
// Round 7 = round 6 + three changes:
//  1. __launch_bounds__(256,3) on k_gru/k_xproj (VGPR cap 170, 3 blocks/CU,
//     LDS 42/45KB fits): round 6 showed the kc GEMM loop is NOT the critical
//     path; the epilogue's HBM loads are latency-bound at 2 waves/SIMD.
//  2. h16 carrier gains a t dimension (ws region, 671MB of the 3.85GB ws).
//  3. k_lseq A-stage = DMA of h16 hi-plane (bit-identical bytes to its old
//     fp32->f16 conversion) -> half the A traffic, zero cvt VALU. Blocks
//     remapped to (t, b-tile) so h16 tiles are contiguous.
// Round-4 lesson: launch_bounds 2nd arg is waves/SIMD (VGPR cap 512/w).
// ---------------------------------------------------------------------------

namespace {
constexpr int B = 65536, D = 512, H = 256, C = 100, T = 10;

// output layout (flat float elements, reference return order)
constexpr long OUT_LOGITS = 0;
constexpr long OUT_PONDER = (long)B * C;
constexpr long OUT_NUP    = OUT_PONDER + 1;
constexpr long OUT_HSEQ   = OUT_NUP + B;
constexpr long OUT_HALT   = OUT_HSEQ + (long)B * T * H;
constexpr long OUT_LSEQ   = OUT_HALT + (long)B * T;

// weight plane sizes (elements)
constexpr long NIH  = 768L * D;   // 393216
constexpr long NHH  = 768L * H;   // 196608
constexpr long NAUG = 112L * H;   // 28672

// workspace layout (float units)
constexpr long WS_XP   = 0;                          // x_proj [B][768] f32
constexpr long WS_W16  = WS_XP + (long)B * 768;      // f16 planes (2x each W)
constexpr long W_HALV  = 2 * (NIH + NHH + NAUG);
constexpr long WS_HL   = WS_W16 + (W_HALV + 1) / 2;  // step_w [B][T]
constexpr long WS_HP4  = WS_HL + (long)B * T;        // halt partials [T][4][B]
constexpr long WS_NUPB = WS_HP4 + 4L * B * T;
constexpr long WS_REMB = WS_NUPB + B;
constexpr long WS_H16  = WS_REMB + B;                // h16 planes, per t
// h16: [t][btile 512][kc 8][plane 2][r 128][kk 32] halves
constexpr long H16_PER_T = 512L * 65536;             // 33,554,432 halves / t

constexpr float SC = 256.f;            // operand pre-scale 2^8
constexpr float SB = 1.f / 65536.f;    // product scale-back 2^-16 (exact)
} // namespace

typedef __attribute__((ext_vector_type(8))) _Float16 h8;
typedef __attribute__((ext_vector_type(4))) _Float16 h4;
typedef __attribute__((ext_vector_type(4))) float f4;

#define MFMA16(A, Bo, Cc) __builtin_amdgcn_mfma_f32_16x16x32_f16(A, Bo, Cc, 0, 0, 0)
// 3-product 2-split accumulate, smallest first
#define PROD3(a, Ah, Al, Bh, Bl)                                               \
  a = MFMA16(Al, Bh, a);                                                       \
  a = MFMA16(Ah, Bl, a);                                                       \
  a = MFMA16(Ah, Bh, a);

__device__ __forceinline__ float sigmoidf_(float x) {
  if (x >= 0.f) { return 1.f / (1.f + expf(-x)); }
  float e = expf(x);
  return e / (1.f + e);
}

// async global->LDS DMA, 16 B per lane; lds base wave-uniform, fills
// base + lane*16 linearly; global src is per-lane.
__device__ __forceinline__ void gload_lds16(const _Float16* g, _Float16* l) {
  __builtin_amdgcn_global_load_lds(
      (const __attribute__((address_space(1))) unsigned int*)g,
      (__attribute__((address_space(3))) unsigned int*)l, 16, 0, 0);
}

// ---------------------------------------------------------------------------
// split weights (pre-scaled by 2^8) into f16 hi/lo planes
__global__ void k_prep(const float* __restrict__ wih_s, const float* __restrict__ whh_s,
                       const float* __restrict__ wro, const float* __restrict__ whalt,
                       _Float16* __restrict__ wr) {
  long idx = (long)blockIdx.x * 256 + threadIdx.x;
  if (idx < NIH) {
    float xs = wih_s[idx] * SC;
    _Float16 h = (_Float16)xs;
    _Float16 l = (_Float16)(xs - (float)h);
    wr[idx] = h; wr[NIH + idx] = l;
  }
  if (idx < NHH) {
    float xs = whh_s[idx] * SC;
    _Float16 h = (_Float16)xs;
    _Float16 l = (_Float16)(xs - (float)h);
    long b = 2 * NIH;
    wr[b + idx] = h; wr[b + NHH + idx] = l;
  }
  if (idx < NAUG) {
    int row = (int)(idx >> 8), k = (int)(idx & 255);
    float x = (row < C) ? wro[row * 256 + k] : ((row == C) ? whalt[k] : 0.f);
    float xs = x * SC;
    _Float16 h = (_Float16)xs;
    _Float16 l = (_Float16)(xs - (float)h);
    long b = 2 * (NIH + NHH);
    wr[b + idx] = h; wr[b + NAUG + idx] = l;
  }
}

// stage 16 fp32 elems (scaled) as f16 hi/lo into LDS at row*40+kk0
__device__ __forceinline__ void stageA16(const float* __restrict__ src,
                                         _Float16* As0, _Float16* As1,
                                         int o) {
#pragma unroll
  for (int i = 0; i < 4; ++i) {
    float4 v = ((const float4*)src)[i];
    float vv[4] = {v.x, v.y, v.z, v.w};
    h4 hh, ll;
#pragma unroll
    for (int c = 0; c < 4; ++c) {
      float sv = vv[c] * SC;
      _Float16 h = (_Float16)sv;
      hh[c] = h;
      ll[c] = (_Float16)(sv - (float)h);
    }
    *(h4*)&As0[o + i * 4] = hh;
    *(h4*)&As1[o + i * 4] = ll;
  }
}

// ---------------------------------------------------------------------------
// xp = x @ W_ih^T + b_ih.  Grid 2048 (XCD-swizzled: 512 row-tiles x 4 strips).
__global__ __launch_bounds__(256, 3) void k_xproj(
    const float* __restrict__ x, const _Float16* __restrict__ wih,
    const float* __restrict__ b_ih, float* __restrict__ xp) {
  __shared__ __align__(16) _Float16 As0[128 * 40], As1[128 * 40];
  __shared__ __align__(16) _Float16 Bs[2][192 * 32];
  const int tid = threadIdx.x;
  const int w = tid >> 6, l = tid & 63;
  const int lr = l & 15, lq = l >> 4;
  const int bid = blockIdx.x;
  const int gid = (bid & 7) * 256 + (bid >> 3);   // XCD-contiguous
  const int c0 = (gid & 3) * 64;
  const int rb = (gid >> 2) * 128;

  f4 acc[8][3];
#pragma unroll
  for (int i = 0; i < 8; ++i)
#pragma unroll
    for (int g = 0; g < 3; ++g) acc[i][g] = (f4)0.f;

  for (int kc = 0; kc < 16; ++kc) {
    const int k0 = kc * 32;
    __syncthreads();
    {  // stage A (x rows, scaled split)
      const int row = tid >> 1, kk0 = (tid & 1) * 16;
      stageA16(x + (long)(rb + row) * D + k0 + kk0, As0, As1, row * 40 + kk0);
    }
    // stage B via async DMA: 2 planes x 12 KB, 6 x 1KB chunks per wave
#pragma unroll
    for (int j = 0; j < 6; ++j) {
      int chunk = w * 6 + j;           // 0..23
      int plane = chunk / 12;
      int rem = chunk - plane * 12;
      int scol = rem * 16 + (l >> 2);
      int kq = l & 3;
      int gcol = (scol >> 6) * 256 + c0 + (scol & 63);
      gload_lds16(wih + (long)plane * NIH + (long)gcol * D + k0 + kq * 8,
                  &Bs[plane][rem * 512]);
    }
    __syncthreads();
    h8 Bh[3], Bl[3];
#pragma unroll
    for (int g = 0; g < 3; ++g) {
      Bh[g] = *(const h8*)&Bs[0][(g * 64 + w * 16 + lr) * 32 + lq * 8];
      Bl[g] = *(const h8*)&Bs[1][(g * 64 + w * 16 + lr) * 32 + lq * 8];
    }
#pragma unroll
    for (int i = 0; i < 8; ++i) {
      h8 Ah = *(const h8*)&As0[(i * 16 + lr) * 40 + lq * 8];
      h8 Al = *(const h8*)&As1[(i * 16 + lr) * 40 + lq * 8];
#pragma unroll
      for (int g = 0; g < 3; ++g) { PROD3(acc[i][g], Ah, Al, Bh[g], Bl[g]); }
    }
  }
  const int ch = c0 + w * 16 + lr;
  float bi[3] = {b_ih[ch], b_ih[256 + ch], b_ih[512 + ch]};
#pragma unroll
  for (int i = 0; i < 8; ++i)
#pragma unroll
    for (int g = 0; g < 3; ++g)
#pragma unroll
      for (int reg = 0; reg < 4; ++reg) {
        long row = rb + i * 16 + lq * 4 + reg;
        xp[row * 768 + g * 256 + ch] = fmaf(acc[i][g][reg], SB, bi[g]);
      }
}

// ---------------------------------------------------------------------------
// One GRU step + fp32-exact halt partial dot per 64-col strip.
// A-operand comes pre-split/pre-tiled from h16[t-1]; epilogue writes h16[t].
__global__ __launch_bounds__(256, 3) void k_gru(
    const _Float16* __restrict__ whh, const float* __restrict__ xp,
    const float* __restrict__ b_hh, const float* __restrict__ w_halt,
    float* __restrict__ out, _Float16* __restrict__ h16,
    float* __restrict__ hp4, int t) {
  __shared__ __align__(16) _Float16 As[2][128 * 32];
  __shared__ __align__(16) _Float16 Bs[2][192 * 32];
  __shared__ float lds_hp[128][4];
  const int tid = threadIdx.x;
  const int w = tid >> 6, l = tid & 63;
  const int lr = l & 15, lq = l >> 4;
  const int bid = blockIdx.x;
  const int gid = (bid & 7) * 256 + (bid >> 3);
  const int strip = gid & 3;
  const int c0 = strip * 64;
  const int rb = (gid >> 2) * 128;
  const long tilebase = (long)(rb >> 7) * 65536;   // 8 kc * 2 planes * 4096

  f4 acc[8][3];
#pragma unroll
  for (int i = 0; i < 8; ++i)
#pragma unroll
    for (int g = 0; g < 3; ++g) acc[i][g] = (f4)0.f;

  if (t > 0) {
    const _Float16* h16r = h16 + (long)(t - 1) * H16_PER_T + tilebase;
    for (int kc = 0; kc < 8; ++kc) {
      const int k0 = kc * 32;
      __syncthreads();
      // stage A via DMA: 2 planes x 8KB = 16 chunks of 1KB; 4 per wave
#pragma unroll
      for (int j = 0; j < 4; ++j) {
        int c8 = w * 4 + j;          // 0..15
        int plane = c8 >> 3;
        int c = c8 & 7;
        gload_lds16(h16r + (long)kc * 8192 + plane * 4096 + c * 512 + l * 8,
                    &As[plane][c * 512]);
      }
      // stage B via DMA
#pragma unroll
      for (int j = 0; j < 6; ++j) {
        int chunk = w * 6 + j;
        int plane = chunk / 12;
        int rem = chunk - plane * 12;
        int scol = rem * 16 + (l >> 2);
        int kq = l & 3;
        int gcol = (scol >> 6) * 256 + c0 + (scol & 63);
        gload_lds16(whh + (long)plane * NHH + (long)gcol * H + k0 + kq * 8,
                    &Bs[plane][rem * 512]);
      }
      __syncthreads();
      h8 Bh[3], Bl[3];
#pragma unroll
      for (int g = 0; g < 3; ++g) {
        Bh[g] = *(const h8*)&Bs[0][(g * 64 + w * 16 + lr) * 32 + lq * 8];
        Bl[g] = *(const h8*)&Bs[1][(g * 64 + w * 16 + lr) * 32 + lq * 8];
      }
#pragma unroll
      for (int i = 0; i < 8; ++i) {
        h8 Ah = *(const h8*)&As[0][(i * 16 + lr) * 32 + lq * 8];
        h8 Al = *(const h8*)&As[1][(i * 16 + lr) * 32 + lq * 8];
#pragma unroll
        for (int g = 0; g < 3; ++g) { PROD3(acc[i][g], Ah, Al, Bh[g], Bl[g]); }
      }
    }
  }

  // epilogue: gates + h_new + h16 planes + halt partial
  const int ch = c0 + w * 16 + lr;
  const float bhr = b_hh[ch], bhz = b_hh[256 + ch], bhn = b_hh[512 + ch];
  const float whv = w_halt[ch];
  // h16 write base for this thread's column: [t][tile][ch>>5][plane][r][ch&31]
  const long h16c = (long)t * H16_PER_T + tilebase + (long)(ch >> 5) * 8192 + (ch & 31);
#pragma unroll
  for (int i = 0; i < 8; ++i)
#pragma unroll
    for (int reg = 0; reg < 4; ++reg) {
      const int rloc = i * 16 + lq * 4 + reg;
      const long row = rb + rloc;
      float xr = xp[row * 768 + ch];
      float xz = xp[row * 768 + 256 + ch];
      float xn = xp[row * 768 + 512 + ch];
      float ho = (t > 0) ? out[OUT_HSEQ + row * (T * H) + (long)(t - 1) * H + ch] : 0.f;
      float rr = sigmoidf_(xr + fmaf(acc[i][0][reg], SB, bhr));
      float zz = sigmoidf_(xz + fmaf(acc[i][1][reg], SB, bhz));
      float nn = tanhf(xn + rr * fmaf(acc[i][2][reg], SB, bhn));
      float hv = (1.f - zz) * nn + zz * ho;
      out[OUT_HSEQ + row * (T * H) + (long)t * H + ch] = hv;
      // pre-split/pre-tiled carrier for next step's A-DMA and k_lseq
      float sv = hv * SC;
      _Float16 hi = (_Float16)sv;
      _Float16 lo = (_Float16)(sv - (float)hi);
      h16[h16c + (long)rloc * 32] = hi;
      h16[h16c + 4096 + (long)rloc * 32] = lo;
      // halt partial over this wave's 16 cols (fp32 shuffle tree)
      float p = hv * whv;
#pragma unroll
      for (int m = 1; m < 16; m <<= 1) p += __shfl_xor(p, m, 64);
      if (lr == 0) lds_hp[rloc][w] = p;
    }
  __syncthreads();
  if (tid < 128)
    hp4[((long)t * 4 + strip) * B + rb + tid] =
        ((lds_hp[tid][0] + lds_hp[tid][1]) + (lds_hp[tid][2] + lds_hp[tid][3]));
}

// ---------------------------------------------------------------------------
// Readout: [B*T,256] x [256,112] single-product f16 (cols 0..99 kept).
// A = h16 hi-plane via DMA (bit-identical to old fp32->f16 conversion).
// Block = (t, 128-row b-tile); grid 512*T.
__global__ __launch_bounds__(256, 4) void k_lseq(
    const _Float16* __restrict__ h16, const _Float16* __restrict__ waug,
    const float* __restrict__ b_ro, float* __restrict__ lseq) {
  __shared__ __align__(16) _Float16 As[128 * 32];
  __shared__ __align__(16) _Float16 Bs[112 * 32];
  const int tid = threadIdx.x;
  const int w = tid >> 6, l = tid & 63;
  const int lr = l & 15, lq = l >> 4;
  const int t = blockIdx.x >> 9;
  const int btile = blockIdx.x & 511;
  const _Float16* h16r = h16 + (long)t * H16_PER_T + (long)btile * 65536;

  f4 acc[2][7];
#pragma unroll
  for (int i = 0; i < 2; ++i)
#pragma unroll
    for (int j = 0; j < 7; ++j) acc[i][j] = (f4)0.f;

  for (int kc = 0; kc < 8; ++kc) {
    const int k0 = kc * 32;
    __syncthreads();
    // stage A hi-plane via DMA: 8KB = 8 x 1KB chunks, 2 per wave
#pragma unroll
    for (int j = 0; j < 2; ++j) {
      int c = w * 2 + j;
      gload_lds16(h16r + (long)kc * 8192 + c * 512 + l * 8, &As[c * 512]);
    }
    // stage B hi-plane via async DMA: 7 x 1KB chunks
#pragma unroll
    for (int j = 0; j < 2; ++j) {
      int chunk = w + j * 4;
      if (chunk < 7) {
        int scol = chunk * 16 + (l >> 2);
        int kq = l & 3;
        gload_lds16(waug + (long)scol * H + k0 + kq * 8, &Bs[chunk * 512]);
      }
    }
    __syncthreads();
    h8 Af[2];
#pragma unroll
    for (int i = 0; i < 2; ++i)
      Af[i] = *(const h8*)&As[(w * 32 + i * 16 + lr) * 32 + lq * 8];
#pragma unroll
    for (int j = 0; j < 7; ++j) {
      h8 Bf = *(const h8*)&Bs[(j * 16 + lr) * 32 + lq * 8];
#pragma unroll
      for (int i = 0; i < 2; ++i) acc[i][j] = MFMA16(Af[i], Bf, acc[i][j]);
    }
  }
#pragma unroll
  for (int j = 0; j < 7; ++j) {
    const int col = j * 16 + lr;
    if (col < C) {
      const float br = b_ro[col];
#pragma unroll
      for (int i = 0; i < 2; ++i)
#pragma unroll
        for (int reg = 0; reg < 4; ++reg) {
          long b = (long)btile * 128 + w * 32 + i * 16 + lq * 4 + reg;
          lseq[(b * T + t) * C + col] = fmaf(acc[i][j][reg], SB, br);
        }
    }
  }
}

// ---------------------------------------------------------------------------
// Per-row: halt[t] = sigmoid(b_halt + 4 strip partials), then ACT chain.
__global__ void k_act(const float* __restrict__ hp4, const float* __restrict__ b_halt,
                      float* __restrict__ out, float* __restrict__ swb,
                      float* __restrict__ nupb, float* __restrict__ remb) {
  const long b = (long)blockIdx.x * 256 + threadIdx.x;
  const float bh = b_halt[0];
  float cum = 0.f, rem = 0.f, nu = 0.f;
#pragma unroll
  for (int t = 0; t < T; ++t) {
    float v = bh + hp4[((long)t * 4 + 0) * B + b] + hp4[((long)t * 4 + 1) * B + b] +
              hp4[((long)t * 4 + 2) * B + b] + hp4[((long)t * 4 + 3) * B + b];
    float halt = sigmoidf_(v);
    out[OUT_HALT + b * T + t] = halt;
    float still = (cum < 0.99f) ? 1.f : 0.f;
    float nh = halt * still;
    float would = ((cum + nh) > 0.99f) ? 1.f : 0.f;
    float rema = (1.f - cum) * would * still;
    float swv = nh * (1.f - would) + rema;
    cum += swv; rem += rema; nu += still;
    swb[b * T + t] = swv;
  }
  nupb[b] = nu; remb[b] = rem;
}

// ---------------------------------------------------------------------------
__global__ void k_logits(const float* __restrict__ lseq, const float* __restrict__ swb,
                         const float* __restrict__ b_ro, const float* __restrict__ nupb,
                         float* __restrict__ out) {
  const long b = blockIdx.x;
  const int tid = threadIdx.x;
  if (tid < C) {
    float br = b_ro[tid];
    float s = br;
#pragma unroll
    for (int t = 0; t < T; ++t) {
      float sw = swb[b * T + t];
      s = fmaf(sw, lseq[(b * T + t) * C + tid] - br, s);
    }
    out[OUT_LOGITS + b * C + tid] = s;
  } else if (tid == C) {
    out[OUT_NUP + b] = nupb[b];
  }
}

// ---------------------------------------------------------------------------
__global__ void k_ponder(const float* __restrict__ nupb, const float* __restrict__ remb,
                         float* __restrict__ out) {
  __shared__ float sm[4];
  float s = 0.f;
  for (int i = threadIdx.x; i < B; i += 256) s += nupb[i] + remb[i];
#pragma unroll
  for (int m = 1; m < 64; m <<= 1) s += __shfl_xor(s, m, 64);
  int w = threadIdx.x >> 6;
  if ((threadIdx.x & 63) == 0) sm[w] = s;
  __syncthreads();
  if (threadIdx.x == 0)
    out[OUT_PONDER] = (sm[0] + sm[1] + sm[2] + sm[3]) * (1.f / (float)B);
}

// ---------------------------------------------------------------------------
extern "C" void kernel_launch(void* const* d_in, const int* in_sizes, int n_in,
                              void* d_out, int out_size, void* d_ws, size_t ws_size,
                              hipStream_t stream) {
  const float* x      = (const float*)d_in[0];
  const float* W_ih   = (const float*)d_in[1];
  const float* W_hh   = (const float*)d_in[2];
  const float* b_ih   = (const float*)d_in[3];
  const float* b_hh   = (const float*)d_in[4];
  const float* W_halt = (const float*)d_in[5];
  const float* b_halt = (const float*)d_in[6];
  const float* W_ro   = (const float*)d_in[7];
  const float* b_ro   = (const float*)d_in[8];
  float* out = (float*)d_out;
  float* ws  = (float*)d_ws;

  float* xp        = ws + WS_XP;
  _Float16* w16    = (_Float16*)(ws + WS_W16);
  _Float16* wih16  = w16;
  _Float16* whh16  = w16 + 2 * NIH;
  _Float16* waug16 = w16 + 2 * (NIH + NHH);
  float* swb  = ws + WS_HL;
  float* hp4  = ws + WS_HP4;
  float* nupb = ws + WS_NUPB;
  float* remb = ws + WS_REMB;
  _Float16* h16 = (_Float16*)(ws + WS_H16);   // per-t pre-split h planes

  k_prep<<<(int)((NIH + 255) / 256), 256, 0, stream>>>(W_ih, W_hh, W_ro, W_halt, w16);
  k_xproj<<<2048, 256, 0, stream>>>(x, wih16, b_ih, xp);
  for (int t = 0; t < T; ++t)
    k_gru<<<2048, 256, 0, stream>>>(whh16, xp, b_hh, W_halt, out, h16, hp4, t);
  k_lseq<<<512 * T, 256, 0, stream>>>(h16, waug16, b_ro, out + OUT_LSEQ);
  k_act<<<B / 256, 256, 0, stream>>>(hp4, b_halt, out, swb, nupb, remb);
  k_logits<<<B, 128, 0, stream>>>(out + OUT_LSEQ, swb, b_ro, nupb, out);
  k_ponder<<<1, 256, 0, stream>>>(nupb, remb, out);
}

// Round 9
// 2192.306 us; speedup vs baseline: 1.5011x; 1.0214x over previous
//
#include <hip/hip_runtime.h>
#include <cmath>

// ---------------------------------------------------------------------------
// ACT classifier (B=65536, D=512, H=256, C=100, T=10).
// Round 9 = round 8 with its two bugs fixed:
//  BUG1: ho recovery used SB (2^-16, the two-operand MFMA scale-back) instead
//        of 1/SC (2^-8, single-operand) -> ho was 256x too small.
//  BUG2: h16 strides kept round-7's 128-row values (plane 4096 / kc 8192)
//        after halving the tile to 64 rows -> tiles overlapped (clobber).
//        Fixed layout: [t][tile 1024][kc 8][plane 2][r 64][kk 32]:
//        plane stride 2048, kc stride 4096, tile stride 32768.
// Structure (unchanged from round-8 plan):
//  - xr/xz folded into MFMA acc init (acc = xp*2^16 exact; ~1e-6 reorder).
//  - ho captured from the As LDS tile at kc == ch>>5 ((hi+lo)/SC, 2^-22 rel).
//  - 64-row tiles, grid 4096, __launch_bounds__(256,4): 4 blocks/CU.
// ---------------------------------------------------------------------------

namespace {
constexpr int B = 65536, D = 512, H = 256, C = 100, T = 10;

// output layout (flat float elements, reference return order)
constexpr long OUT_LOGITS = 0;
constexpr long OUT_PONDER = (long)B * C;
constexpr long OUT_NUP    = OUT_PONDER + 1;
constexpr long OUT_HSEQ   = OUT_NUP + B;
constexpr long OUT_HALT   = OUT_HSEQ + (long)B * T * H;
constexpr long OUT_LSEQ   = OUT_HALT + (long)B * T;

// weight plane sizes (elements)
constexpr long NIH  = 768L * D;   // 393216
constexpr long NHH  = 768L * H;   // 196608
constexpr long NAUG = 112L * H;   // 28672

// workspace layout (float units)
constexpr long WS_XP   = 0;                          // x_proj [B][768] f32
constexpr long WS_W16  = WS_XP + (long)B * 768;      // f16 planes (2x each W)
constexpr long W_HALV  = 2 * (NIH + NHH + NAUG);
constexpr long WS_HL   = WS_W16 + (W_HALV + 1) / 2;  // step_w [B][T]
constexpr long WS_HP4  = WS_HL + (long)B * T;        // halt partials [T][4][B]
constexpr long WS_NUPB = WS_HP4 + 4L * B * T;
constexpr long WS_REMB = WS_NUPB + B;
constexpr long WS_H16  = WS_REMB + B;                // h16 planes, per t
// h16: [t][tile 1024][kc 8][plane 2][r 64][kk 32] halves
constexpr long H16_PER_T = 1024L * 32768;            // 33,554,432 halves / t

constexpr float SC  = 256.f;           // operand pre-scale 2^8
constexpr float ISC = 1.f / 256.f;     // single-operand scale-back 2^-8
constexpr float SB  = 1.f / 65536.f;   // product scale-back 2^-16 (exact)
} // namespace

typedef __attribute__((ext_vector_type(8))) _Float16 h8;
typedef __attribute__((ext_vector_type(4))) _Float16 h4;
typedef __attribute__((ext_vector_type(4))) float f4;

#define MFMA16(A, Bo, Cc) __builtin_amdgcn_mfma_f32_16x16x32_f16(A, Bo, Cc, 0, 0, 0)
// 3-product 2-split accumulate, smallest first
#define PROD3(a, Ah, Al, Bh, Bl)                                               \
  a = MFMA16(Al, Bh, a);                                                       \
  a = MFMA16(Ah, Bl, a);                                                       \
  a = MFMA16(Ah, Bh, a);

__device__ __forceinline__ float sigmoidf_(float x) {
  if (x >= 0.f) { return 1.f / (1.f + expf(-x)); }
  float e = expf(x);
  return e / (1.f + e);
}

// async global->LDS DMA, 16 B per lane; lds base wave-uniform, fills
// base + lane*16 linearly; global src is per-lane.
__device__ __forceinline__ void gload_lds16(const _Float16* g, _Float16* l) {
  __builtin_amdgcn_global_load_lds(
      (const __attribute__((address_space(1))) unsigned int*)g,
      (__attribute__((address_space(3))) unsigned int*)l, 16, 0, 0);
}

// ---------------------------------------------------------------------------
// split weights (pre-scaled by 2^8) into f16 hi/lo planes
__global__ void k_prep(const float* __restrict__ wih_s, const float* __restrict__ whh_s,
                       const float* __restrict__ wro, const float* __restrict__ whalt,
                       _Float16* __restrict__ wr) {
  long idx = (long)blockIdx.x * 256 + threadIdx.x;
  if (idx < NIH) {
    float xs = wih_s[idx] * SC;
    _Float16 h = (_Float16)xs;
    _Float16 l = (_Float16)(xs - (float)h);
    wr[idx] = h; wr[NIH + idx] = l;
  }
  if (idx < NHH) {
    float xs = whh_s[idx] * SC;
    _Float16 h = (_Float16)xs;
    _Float16 l = (_Float16)(xs - (float)h);
    long b = 2 * NIH;
    wr[b + idx] = h; wr[b + NHH + idx] = l;
  }
  if (idx < NAUG) {
    int row = (int)(idx >> 8), k = (int)(idx & 255);
    float x = (row < C) ? wro[row * 256 + k] : ((row == C) ? whalt[k] : 0.f);
    float xs = x * SC;
    _Float16 h = (_Float16)xs;
    _Float16 l = (_Float16)(xs - (float)h);
    long b = 2 * (NIH + NHH);
    wr[b + idx] = h; wr[b + NAUG + idx] = l;
  }
}

// stage 16 fp32 elems (scaled) as f16 hi/lo into LDS at row*40+kk0
__device__ __forceinline__ void stageA16(const float* __restrict__ src,
                                         _Float16* As0, _Float16* As1,
                                         int o) {
#pragma unroll
  for (int i = 0; i < 4; ++i) {
    float4 v = ((const float4*)src)[i];
    float vv[4] = {v.x, v.y, v.z, v.w};
    h4 hh, ll;
#pragma unroll
    for (int c = 0; c < 4; ++c) {
      float sv = vv[c] * SC;
      _Float16 h = (_Float16)sv;
      hh[c] = h;
      ll[c] = (_Float16)(sv - (float)h);
    }
    *(h4*)&As0[o + i * 4] = hh;
    *(h4*)&As1[o + i * 4] = ll;
  }
}

// ---------------------------------------------------------------------------
// xp = x @ W_ih^T + b_ih.  Grid 2048 (XCD-swizzled: 512 row-tiles x 4 strips).
__global__ __launch_bounds__(256, 3) void k_xproj(
    const float* __restrict__ x, const _Float16* __restrict__ wih,
    const float* __restrict__ b_ih, float* __restrict__ xp) {
  __shared__ __align__(16) _Float16 As0[128 * 40], As1[128 * 40];
  __shared__ __align__(16) _Float16 Bs[2][192 * 32];
  const int tid = threadIdx.x;
  const int w = tid >> 6, l = tid & 63;
  const int lr = l & 15, lq = l >> 4;
  const int bid = blockIdx.x;
  const int gid = (bid & 7) * 256 + (bid >> 3);   // XCD-contiguous
  const int c0 = (gid & 3) * 64;
  const int rb = (gid >> 2) * 128;

  f4 acc[8][3];
#pragma unroll
  for (int i = 0; i < 8; ++i)
#pragma unroll
    for (int g = 0; g < 3; ++g) acc[i][g] = (f4)0.f;

  for (int kc = 0; kc < 16; ++kc) {
    const int k0 = kc * 32;
    __syncthreads();
    {  // stage A (x rows, scaled split)
      const int row = tid >> 1, kk0 = (tid & 1) * 16;
      stageA16(x + (long)(rb + row) * D + k0 + kk0, As0, As1, row * 40 + kk0);
    }
    // stage B via async DMA: 2 planes x 12 KB, 6 x 1KB chunks per wave
#pragma unroll
    for (int j = 0; j < 6; ++j) {
      int chunk = w * 6 + j;           // 0..23
      int plane = chunk / 12;
      int rem = chunk - plane * 12;
      int scol = rem * 16 + (l >> 2);
      int kq = l & 3;
      int gcol = (scol >> 6) * 256 + c0 + (scol & 63);
      gload_lds16(wih + (long)plane * NIH + (long)gcol * D + k0 + kq * 8,
                  &Bs[plane][rem * 512]);
    }
    __syncthreads();
    h8 Bh[3], Bl[3];
#pragma unroll
    for (int g = 0; g < 3; ++g) {
      Bh[g] = *(const h8*)&Bs[0][(g * 64 + w * 16 + lr) * 32 + lq * 8];
      Bl[g] = *(const h8*)&Bs[1][(g * 64 + w * 16 + lr) * 32 + lq * 8];
    }
#pragma unroll
    for (int i = 0; i < 8; ++i) {
      h8 Ah = *(const h8*)&As0[(i * 16 + lr) * 40 + lq * 8];
      h8 Al = *(const h8*)&As1[(i * 16 + lr) * 40 + lq * 8];
#pragma unroll
      for (int g = 0; g < 3; ++g) { PROD3(acc[i][g], Ah, Al, Bh[g], Bl[g]); }
    }
  }
  const int ch = c0 + w * 16 + lr;
  float bi[3] = {b_ih[ch], b_ih[256 + ch], b_ih[512 + ch]};
#pragma unroll
  for (int i = 0; i < 8; ++i)
#pragma unroll
    for (int g = 0; g < 3; ++g)
#pragma unroll
      for (int reg = 0; reg < 4; ++reg) {
        long row = rb + i * 16 + lq * 4 + reg;
        xp[row * 768 + g * 256 + ch] = fmaf(acc[i][g][reg], SB, bi[g]);
      }
}

// ---------------------------------------------------------------------------
// One GRU step, 64-row tiles. A from h16[t-1] via DMA; xr/xz pre-folded into
// acc; ho captured from LDS; epilogue writes h_seq + h16[t] + halt partial.
// h16 slab strides: plane 2048, kc 4096, tile 32768 (compact, no overlap).
__global__ __launch_bounds__(256, 4) void k_gru(
    const _Float16* __restrict__ whh, const float* __restrict__ xp,
    const float* __restrict__ b_hh, const float* __restrict__ w_halt,
    float* __restrict__ out, _Float16* __restrict__ h16,
    float* __restrict__ hp4, int t) {
  __shared__ __align__(16) _Float16 As[2][64 * 32];
  __shared__ __align__(16) _Float16 Bs[2][192 * 32];
  __shared__ float lds_hp[64][4];
  const int tid = threadIdx.x;
  const int w = tid >> 6, l = tid & 63;
  const int lr = l & 15, lq = l >> 4;
  const int bid = blockIdx.x;
  const int gid = (bid & 7) * 512 + (bid >> 3);   // XCD-contiguous
  const int strip = gid & 3;
  const int c0 = strip * 64;
  const int rb = (gid >> 2) * 64;
  const long tilebase = (long)(rb >> 6) * 32768;  // 8 kc * 2 planes * 2048
  const int ch = c0 + w * 16 + lr;
  const int kc_h = ch >> 5;                       // wave-uniform

  f4 acc[4][3];
  float ho[4][4];
  // init: fold xr,xz into accumulator (exact *2^16), issued before kc loop
#pragma unroll
  for (int i = 0; i < 4; ++i) {
#pragma unroll
    for (int reg = 0; reg < 4; ++reg) {
      long row = rb + i * 16 + lq * 4 + reg;
      acc[i][0][reg] = xp[row * 768 + ch] * 65536.f;
      acc[i][1][reg] = xp[row * 768 + 256 + ch] * 65536.f;
      ho[i][reg] = 0.f;
    }
    acc[i][2] = (f4)0.f;
  }

  if (t > 0) {
    const _Float16* h16r = h16 + (long)(t - 1) * H16_PER_T + tilebase;
    for (int kc = 0; kc < 8; ++kc) {
      const int k0 = kc * 32;
      __syncthreads();
      // stage A via DMA: 2 planes x 4KB = 8 chunks of 1KB; 2 per wave
#pragma unroll
      for (int j = 0; j < 2; ++j) {
        int c = w * 2 + j;          // 0..7
        int plane = c >> 2;
        int cc = c & 3;
        gload_lds16(h16r + (long)kc * 4096 + plane * 2048 + cc * 512 + l * 8,
                    &As[plane][cc * 512]);
      }
      // stage B via DMA: 24 x 1KB chunks, 6 per wave
#pragma unroll
      for (int j = 0; j < 6; ++j) {
        int chunk = w * 6 + j;
        int plane = chunk / 12;
        int rem = chunk - plane * 12;
        int scol = rem * 16 + (l >> 2);
        int kq = l & 3;
        int gcol = (scol >> 6) * 256 + c0 + (scol & 63);
        gload_lds16(whh + (long)plane * NHH + (long)gcol * H + k0 + kq * 8,
                    &Bs[plane][rem * 512]);
      }
      __syncthreads();
      h8 Bh[3], Bl[3];
#pragma unroll
      for (int g = 0; g < 3; ++g) {
        Bh[g] = *(const h8*)&Bs[0][(g * 64 + w * 16 + lr) * 32 + lq * 8];
        Bl[g] = *(const h8*)&Bs[1][(g * 64 + w * 16 + lr) * 32 + lq * 8];
      }
#pragma unroll
      for (int i = 0; i < 4; ++i) {
        h8 Ah = *(const h8*)&As[0][(i * 16 + lr) * 32 + lq * 8];
        h8 Al = *(const h8*)&As[1][(i * 16 + lr) * 32 + lq * 8];
#pragma unroll
        for (int g = 0; g < 3; ++g) { PROD3(acc[i][g], Ah, Al, Bh[g], Bl[g]); }
      }
      // capture ho = h_{t-1}[row, ch] from this kc's As tile: (hi+lo)/SC
      if (kc == kc_h) {
#pragma unroll
        for (int i = 0; i < 4; ++i)
#pragma unroll
          for (int reg = 0; reg < 4; ++reg) {
            int rloc = i * 16 + lq * 4 + reg;
            ho[i][reg] = ((float)As[0][rloc * 32 + (ch & 31)] +
                          (float)As[1][rloc * 32 + (ch & 31)]) * ISC;
          }
      }
    }
  }

  // epilogue: gates + h_new + h16 planes + halt partial (only xn loads)
  const float bhr = b_hh[ch], bhz = b_hh[256 + ch], bhn = b_hh[512 + ch];
  const float whv = w_halt[ch];
  const long h16base = (long)t * H16_PER_T + tilebase + (long)kc_h * 4096 + (ch & 31);
#pragma unroll
  for (int i = 0; i < 4; ++i)
#pragma unroll
    for (int reg = 0; reg < 4; ++reg) {
      const int rloc = i * 16 + lq * 4 + reg;
      const long row = rb + rloc;
      float xn = xp[row * 768 + 512 + ch];
      float rr = sigmoidf_(fmaf(acc[i][0][reg], SB, bhr));
      float zz = sigmoidf_(fmaf(acc[i][1][reg], SB, bhz));
      float nn = tanhf(xn + rr * fmaf(acc[i][2][reg], SB, bhn));
      float hv = (1.f - zz) * nn + zz * ho[i][reg];
      out[OUT_HSEQ + row * (T * H) + (long)t * H + ch] = hv;
      // pre-split/pre-tiled carrier for next step's A-DMA and k_lseq
      float sv = hv * SC;
      _Float16 hi = (_Float16)sv;
      _Float16 lo = (_Float16)(sv - (float)hi);
      h16[h16base + (long)rloc * 32] = hi;
      h16[h16base + 2048 + (long)rloc * 32] = lo;
      // halt partial over this wave's 16 cols (fp32 shuffle tree)
      float p = hv * whv;
#pragma unroll
      for (int m = 1; m < 16; m <<= 1) p += __shfl_xor(p, m, 64);
      if (lr == 0) lds_hp[rloc][w] = p;
    }
  __syncthreads();
  if (tid < 64)
    hp4[((long)t * 4 + strip) * B + rb + tid] =
        ((lds_hp[tid][0] + lds_hp[tid][1]) + (lds_hp[tid][2] + lds_hp[tid][3]));
}

// ---------------------------------------------------------------------------
// Readout: [B*T,256] x [256,112] single-product f16 (cols 0..99 kept).
// A = h16 hi-plane via DMA. Block = (t, 128-row b-tile) = two 64-row tiles.
__global__ __launch_bounds__(256, 4) void k_lseq(
    const _Float16* __restrict__ h16, const _Float16* __restrict__ waug,
    const float* __restrict__ b_ro, float* __restrict__ lseq) {
  __shared__ __align__(16) _Float16 As[128 * 32];
  __shared__ __align__(16) _Float16 Bs[112 * 32];
  const int tid = threadIdx.x;
  const int w = tid >> 6, l = tid & 63;
  const int lr = l & 15, lq = l >> 4;
  const int t = blockIdx.x >> 9;
  const int btile = blockIdx.x & 511;
  const _Float16* h16r = h16 + (long)t * H16_PER_T + (long)btile * 65536;

  f4 acc[2][7];
#pragma unroll
  for (int i = 0; i < 2; ++i)
#pragma unroll
    for (int j = 0; j < 7; ++j) acc[i][j] = (f4)0.f;

  for (int kc = 0; kc < 8; ++kc) {
    const int k0 = kc * 32;
    __syncthreads();
    // stage A hi-plane via DMA: 8 x 1KB chunks (2 tiles x 4), 2 per wave
#pragma unroll
    for (int j = 0; j < 2; ++j) {
      int c = w * 2 + j;   // 0..7; c>>2 selects 64-row tile
      gload_lds16(h16r + (long)(c >> 2) * 32768 + (long)kc * 4096 + (c & 3) * 512 + l * 8,
                  &As[c * 512]);
    }
    // stage B hi-plane via async DMA: 7 x 1KB chunks
#pragma unroll
    for (int j = 0; j < 2; ++j) {
      int chunk = w + j * 4;
      if (chunk < 7) {
        int scol = chunk * 16 + (l >> 2);
        int kq = l & 3;
        gload_lds16(waug + (long)scol * H + k0 + kq * 8, &Bs[chunk * 512]);
      }
    }
    __syncthreads();
    h8 Af[2];
#pragma unroll
    for (int i = 0; i < 2; ++i)
      Af[i] = *(const h8*)&As[(w * 32 + i * 16 + lr) * 32 + lq * 8];
#pragma unroll
    for (int j = 0; j < 7; ++j) {
      h8 Bf = *(const h8*)&Bs[(j * 16 + lr) * 32 + lq * 8];
#pragma unroll
      for (int i = 0; i < 2; ++i) acc[i][j] = MFMA16(Af[i], Bf, acc[i][j]);
    }
  }
#pragma unroll
  for (int j = 0; j < 7; ++j) {
    const int col = j * 16 + lr;
    if (col < C) {
      const float br = b_ro[col];
#pragma unroll
      for (int i = 0; i < 2; ++i)
#pragma unroll
        for (int reg = 0; reg < 4; ++reg) {
          long b = (long)btile * 128 + w * 32 + i * 16 + lq * 4 + reg;
          lseq[(b * T + t) * C + col] = fmaf(acc[i][j][reg], SB, br);
        }
    }
  }
}

// ---------------------------------------------------------------------------
// Per-row: halt[t] = sigmoid(b_halt + 4 strip partials), then ACT chain.
__global__ void k_act(const float* __restrict__ hp4, const float* __restrict__ b_halt,
                      float* __restrict__ out, float* __restrict__ swb,
                      float* __restrict__ nupb, float* __restrict__ remb) {
  const long b = (long)blockIdx.x * 256 + threadIdx.x;
  const float bh = b_halt[0];
  float cum = 0.f, rem = 0.f, nu = 0.f;
#pragma unroll
  for (int t = 0; t < T; ++t) {
    float v = bh + hp4[((long)t * 4 + 0) * B + b] + hp4[((long)t * 4 + 1) * B + b] +
              hp4[((long)t * 4 + 2) * B + b] + hp4[((long)t * 4 + 3) * B + b];
    float halt = sigmoidf_(v);
    out[OUT_HALT + b * T + t] = halt;
    float still = (cum < 0.99f) ? 1.f : 0.f;
    float nh = halt * still;
    float would = ((cum + nh) > 0.99f) ? 1.f : 0.f;
    float rema = (1.f - cum) * would * still;
    float swv = nh * (1.f - would) + rema;
    cum += swv; rem += rema; nu += still;
    swb[b * T + t] = swv;
  }
  nupb[b] = nu; remb[b] = rem;
}

// ---------------------------------------------------------------------------
__global__ void k_logits(const float* __restrict__ lseq, const float* __restrict__ swb,
                         const float* __restrict__ b_ro, const float* __restrict__ nupb,
                         float* __restrict__ out) {
  const long b = blockIdx.x;
  const int tid = threadIdx.x;
  if (tid < C) {
    float br = b_ro[tid];
    float s = br;
#pragma unroll
    for (int t = 0; t < T; ++t) {
      float sw = swb[b * T + t];
      s = fmaf(sw, lseq[(b * T + t) * C + tid] - br, s);
    }
    out[OUT_LOGITS + b * C + tid] = s;
  } else if (tid == C) {
    out[OUT_NUP + b] = nupb[b];
  }
}

// ---------------------------------------------------------------------------
__global__ void k_ponder(const float* __restrict__ nupb, const float* __restrict__ remb,
                         float* __restrict__ out) {
  __shared__ float sm[4];
  float s = 0.f;
  for (int i = threadIdx.x; i < B; i += 256) s += nupb[i] + remb[i];
#pragma unroll
  for (int m = 1; m < 64; m <<= 1) s += __shfl_xor(s, m, 64);
  int w = threadIdx.x >> 6;
  if ((threadIdx.x & 63) == 0) sm[w] = s;
  __syncthreads();
  if (threadIdx.x == 0)
    out[OUT_PONDER] = (sm[0] + sm[1] + sm[2] + sm[3]) * (1.f / (float)B);
}

// ---------------------------------------------------------------------------
extern "C" void kernel_launch(void* const* d_in, const int* in_sizes, int n_in,
                              void* d_out, int out_size, void* d_ws, size_t ws_size,
                              hipStream_t stream) {
  const float* x      = (const float*)d_in[0];
  const float* W_ih   = (const float*)d_in[1];
  const float* W_hh   = (const float*)d_in[2];
  const float* b_ih   = (const float*)d_in[3];
  const float* b_hh   = (const float*)d_in[4];
  const float* W_halt = (const float*)d_in[5];
  const float* b_halt = (const float*)d_in[6];
  const float* W_ro   = (const float*)d_in[7];
  const float* b_ro   = (const float*)d_in[8];
  float* out = (float*)d_out;
  float* ws  = (float*)d_ws;

  float* xp        = ws + WS_XP;
  _Float16* w16    = (_Float16*)(ws + WS_W16);
  _Float16* wih16  = w16;
  _Float16* whh16  = w16 + 2 * NIH;
  _Float16* waug16 = w16 + 2 * (NIH + NHH);
  float* swb  = ws + WS_HL;
  float* hp4  = ws + WS_HP4;
  float* nupb = ws + WS_NUPB;
  float* remb = ws + WS_REMB;
  _Float16* h16 = (_Float16*)(ws + WS_H16);   // per-t pre-split h planes

  k_prep<<<(int)((NIH + 255) / 256), 256, 0, stream>>>(W_ih, W_hh, W_ro, W_halt, w16);
  k_xproj<<<2048, 256, 0, stream>>>(x, wih16, b_ih, xp);
  for (int t = 0; t < T; ++t)
    k_gru<<<4096, 256, 0, stream>>>(whh16, xp, b_hh, W_halt, out, h16, hp4, t);
  k_lseq<<<512 * T, 256, 0, stream>>>(h16, waug16, b_ro, out + OUT_LSEQ);
  k_act<<<B / 256, 256, 0, stream>>>(hp4, b_halt, out, swb, nupb, remb);
  k_logits<<<B, 128, 0, stream>>>(out + OUT_LSEQ, swb, b_ro, nupb, out);
  k_ponder<<<1, 256, 0, stream>>>(nupb, remb, out);
}